// Round 9
// baseline (2531.587 us; speedup 1.0000x reference)
//
#include <hip/hip_runtime.h>
#include <hip/hip_bf16.h>
#include <math.h>

// AttentiveFP forward. Split-bf16 (3-term) MFMA engine.
//  - activations stored as packed u32 (bf16 hi | bf16 lo) -> no consumer split
//  - fused e-on-the-fly edge kernel (32KB swizzled LDS), rowdot pass A /
//    att-scatter pass B; sum(att)=1 Wat move (+ empty-segment rowmask)
//  - fused GRU (gate-sliced packed weights)
// H=128, 3H=384.

#define HD 128
#define H3 384

typedef __attribute__((ext_vector_type(8))) short short8;
typedef __attribute__((ext_vector_type(4))) float f32x4;

__device__ __forceinline__ float lrelu_f(float x) { return x > 0.f ? x : 0.01f * x; }
__device__ __forceinline__ float sigmoid_f(float x) { return 1.f / (1.f + expf(-x)); }

__device__ __forceinline__ void atomicMaxF(float* addr, float val) {
    int iv = __float_as_int(val);
    if (iv >= 0) atomicMax((int*)addr, iv);
    else atomicMin((unsigned int*)addr, (unsigned int)iv);
}

__device__ __forceinline__ unsigned short bf16_rne(float v, float* back) {
    unsigned u = __float_as_uint(v);
    unsigned r = (u + 0x7FFFu + ((u >> 16) & 1u)) >> 16;
    *back = __uint_as_float(r << 16);
    return (unsigned short)r;
}

// pack f32 -> (bf16_hi << 16) | bf16_lo, lo = bf16(v - f32(hi))
__device__ __forceinline__ unsigned pack_hl(float v) {
    float back, d;
    unsigned short h = bf16_rne(v, &back);
    unsigned short l = bf16_rne(v - back, &d);
    return ((unsigned)h << 16) | (unsigned)l;
}
__device__ __forceinline__ float unpack_f32(unsigned w) {
    return __uint_as_float(w & 0xffff0000u) + __uint_as_float(w << 16);
}

__device__ __forceinline__ void split8(const float* p, short8& h8, short8& l8) {
    float4 u0 = *reinterpret_cast<const float4*>(p);
    float4 u1 = *reinterpret_cast<const float4*>(p + 4);
    float vv[8] = {u0.x, u0.y, u0.z, u0.w, u1.x, u1.y, u1.z, u1.w};
#pragma unroll
    for (int j = 0; j < 8; ++j) {
        float back, d;
        h8[j] = (short)bf16_rne(vv[j], &back);
        l8[j] = (short)bf16_rne(vv[j] - back, &d);
    }
}

// unpack 8 packed u32 (32B, two uint4) -> hi/lo short8
__device__ __forceinline__ void unpack8(const unsigned* p, short8& h8, short8& l8) {
    uint4 w0 = *reinterpret_cast<const uint4*>(p);
    uint4 w1 = *reinterpret_cast<const uint4*>(p + 4);
    unsigned ww[8] = {w0.x, w0.y, w0.z, w0.w, w1.x, w1.y, w1.z, w1.w};
#pragma unroll
    for (int j = 0; j < 8; ++j) {
        h8[j] = (short)(ww[j] >> 16);
        l8[j] = (short)(ww[j] & 0xffffu);
    }
}

// ---------------------------------------------------------------------------
// Pack B[K x Ncols] (row stride ldb, start col col0) into MFMA frag order:
// [nblk][kg][col16][e8], KG = 4*ceil(K/32). Zero-pad k >= K.
// ---------------------------------------------------------------------------
__global__ void pack_b_kernel(const float* __restrict__ B, int K, int ldb, int col0,
                              int Ncols, short* __restrict__ hi, short* __restrict__ lo) {
    int KG = 4 * ((K + 31) / 32);
    int idx = blockIdx.x * blockDim.x + threadIdx.x;
    int total = (Ncols >> 4) * KG * 16;
    if (idx >= total) return;
    int col = idx & 15;
    int kg = (idx >> 4) % KG;
    int nblk = idx / (16 * KG);
    size_t o = (size_t)idx * 8;
#pragma unroll
    for (int e = 0; e < 8; ++e) {
        int k = kg * 8 + e;
        float v = (k < K) ? B[(size_t)k * ldb + col0 + nblk * 16 + col] : 0.f;
        float hf, d;
        unsigned short h = bf16_rne(v, &hf);
        unsigned short l = bf16_rne(v - hf, &d);
        hi[o + e] = (short)h;
        lo[o + e] = (short)l;
    }
}

// ---------------------------------------------------------------------------
// Generic split-bf16 GEMM: C = act(A[M,K] @ B + bias), act 0/1(lrelu)/2(relu)/3(elu)
// outpk: 1 -> C stored as packed u32 hi/lo (MFMA-consumer format)
// rowdot: rdout[m] += sum_c rdw[c]*v (atomic, post-act)
// rowmask: rows with rowmask[m]==0 output exactly 0 (empty segments)
// ---------------------------------------------------------------------------
__global__ __launch_bounds__(256) void mfma_gemm(
    const float* __restrict__ A, int K,
    const short* __restrict__ Bhi, const short* __restrict__ Blo, int KG,
    const float* __restrict__ bias, float* __restrict__ C, int M, int N, int act,
    const float* __restrict__ rdw, float* __restrict__ rdout,
    const float* __restrict__ rowmask, int outpk)
{
    const int t = threadIdx.x, lane = t & 63, w = t >> 6;
    const int wm = w & 1, wn = w >> 1, q = lane >> 4, r16 = lane & 15;
    const int m0 = blockIdx.x * 64, n0 = blockIdx.y * 64;
    const int KT = K >> 5;

    f32x4 acc[2][2];
#pragma unroll
    for (int a = 0; a < 2; ++a)
#pragma unroll
        for (int b = 0; b < 2; ++b) { acc[a][b][0]=0.f; acc[a][b][1]=0.f; acc[a][b][2]=0.f; acc[a][b][3]=0.f; }

    int arow[2];
#pragma unroll
    for (int mt = 0; mt < 2; ++mt) {
        int m = m0 + (wm << 5) + (mt << 4) + r16;
        arow[mt] = (m >= M) ? M - 1 : m;
    }

    for (int kt = 0; kt < KT; ++kt) {
        short8 ah[2], al[2];
#pragma unroll
        for (int mt = 0; mt < 2; ++mt)
            split8(A + (size_t)arow[mt] * K + (kt << 5) + (q << 3), ah[mt], al[mt]);
        const int kg = (kt << 2) + q;
#pragma unroll
        for (int nt = 0; nt < 2; ++nt) {
            int nblk = (n0 >> 4) + (wn << 1) + nt;
            size_t boff = (((size_t)nblk * KG + kg) * 16 + r16) * 8;
            short8 bh = *reinterpret_cast<const short8*>(Bhi + boff);
            short8 bl = *reinterpret_cast<const short8*>(Blo + boff);
#pragma unroll
            for (int mt = 0; mt < 2; ++mt) {
                acc[mt][nt] = __builtin_amdgcn_mfma_f32_16x16x32_bf16(ah[mt], bh, acc[mt][nt], 0, 0, 0);
                acc[mt][nt] = __builtin_amdgcn_mfma_f32_16x16x32_bf16(ah[mt], bl, acc[mt][nt], 0, 0, 0);
                acc[mt][nt] = __builtin_amdgcn_mfma_f32_16x16x32_bf16(al[mt], bh, acc[mt][nt], 0, 0, 0);
            }
        }
    }

#pragma unroll
    for (int mt = 0; mt < 2; ++mt) {
        float pv[4] = {0.f, 0.f, 0.f, 0.f};
#pragma unroll
        for (int nt = 0; nt < 2; ++nt) {
            int col = n0 + (wn << 5) + (nt << 4) + r16;
            float bi = bias ? bias[col] : 0.f;
            float wc = rdw ? rdw[col] : 0.f;
#pragma unroll
            for (int i = 0; i < 4; ++i) {
                int m = m0 + (wm << 5) + (mt << 4) + (q << 2) + i;
                float v = acc[mt][nt][i] + bi;
                if (act == 1) v = v > 0.f ? v : 0.01f * v;
                else if (act == 2) v = fmaxf(v, 0.f);
                else if (act == 3) v = v > 0.f ? v : expf(v) - 1.f;
                if (rowmask && m < M && rowmask[m] == 0.f) v = 0.f;
                pv[i] += wc * v;
                if (m < M) {
                    if (outpk) ((unsigned*)C)[(size_t)m * N + col] = pack_hl(v);
                    else C[(size_t)m * N + col] = v;
                }
            }
        }
        if (rdw) {
#pragma unroll
            for (int i = 0; i < 4; ++i) {
                float p = pv[i];
                p += __shfl_xor(p, 1); p += __shfl_xor(p, 2);
                p += __shfl_xor(p, 4); p += __shfl_xor(p, 8);
                int m = m0 + (wm << 5) + (mt << 4) + (q << 2) + i;
                if (r16 == 0 && m < M) atomicAdd(&rdout[m], p);
            }
        }
    }
}

// ---------------------------------------------------------------------------
// Fused edge kernel. Block = 64 edges x 128 msg cols. 4 waves.
// Stage 1: e = lrelu(edge_raw @ We0 + be0) -> LDS packed u32, stride 128,
//          XOR swizzle c ^= (row&7)<<2  (32 KB -> 5 WG/CU).
// Stage 2: msg = lrelu([h[src], e] @ We + be) in acc; h read packed.
// pass 0: sc[m] += msg . wal   pass 1: S[dst[m]] += sc[m] * msg
// ---------------------------------------------------------------------------
__global__ __launch_bounds__(256) void msg_pass_kernel(
    const unsigned* __restrict__ hpk, const int* __restrict__ src, const int* __restrict__ dst,
    const float* __restrict__ edge,
    const short* __restrict__ W0hi, const short* __restrict__ W0lo,
    const float* __restrict__ be0,
    const short* __restrict__ Wehi, const short* __restrict__ Welo,
    const float* __restrict__ be,
    const float* __restrict__ wal,
    float* __restrict__ sc, float* __restrict__ S,
    int E, int pass)
{
    __shared__ unsigned int elds[64 * 128];
    const int t = threadIdx.x, lane = t & 63, w = t >> 6;
    const int wm = w & 1, wn = w >> 1, q = lane >> 4, r16 = lane & 15;
    const int e0 = blockIdx.x * 64;

    // ---- stage 1: e tile ----
    {
        f32x4 ea[2][4];
#pragma unroll
        for (int a = 0; a < 2; ++a)
#pragma unroll
            for (int b = 0; b < 4; ++b) { ea[a][b][0]=0.f; ea[a][b][1]=0.f; ea[a][b][2]=0.f; ea[a][b][3]=0.f; }
        short8 eah[2], eal[2];
#pragma unroll
        for (int mt = 0; mt < 2; ++mt) {
            int er = e0 + (wm << 5) + (mt << 4) + r16;
            if (er >= E) er = E - 1;
            if (q < 2) split8(edge + (size_t)er * 16 + (q << 3), eah[mt], eal[mt]);
            else {
#pragma unroll
                for (int j = 0; j < 8; ++j) { eah[mt][j] = 0; eal[mt][j] = 0; }
            }
        }
#pragma unroll
        for (int nt = 0; nt < 4; ++nt) {
            int nblk = (wn << 2) + nt;
            size_t boff = (((size_t)nblk * 4 + q) * 16 + r16) * 8;
            short8 bh = *reinterpret_cast<const short8*>(W0hi + boff);
            short8 bl = *reinterpret_cast<const short8*>(W0lo + boff);
#pragma unroll
            for (int mt = 0; mt < 2; ++mt) {
                ea[mt][nt] = __builtin_amdgcn_mfma_f32_16x16x32_bf16(eah[mt], bh, ea[mt][nt], 0, 0, 0);
                ea[mt][nt] = __builtin_amdgcn_mfma_f32_16x16x32_bf16(eah[mt], bl, ea[mt][nt], 0, 0, 0);
                ea[mt][nt] = __builtin_amdgcn_mfma_f32_16x16x32_bf16(eal[mt], bh, ea[mt][nt], 0, 0, 0);
            }
        }
#pragma unroll
        for (int mt = 0; mt < 2; ++mt)
#pragma unroll
            for (int nt = 0; nt < 4; ++nt) {
                int col = (wn << 6) + (nt << 4) + r16;
#pragma unroll
                for (int i = 0; i < 4; ++i) {
                    int row = (wm << 5) + (mt << 4) + (q << 2) + i;
                    float v = lrelu_f(ea[mt][nt][i] + be0[col]);
                    elds[row * 128 + (col ^ ((row & 7) << 2))] = pack_hl(v);
                }
            }
    }
    __syncthreads();

    // ---- stage 2: msg ----
    f32x4 acc[2][4];
#pragma unroll
    for (int a = 0; a < 2; ++a)
#pragma unroll
        for (int b = 0; b < 4; ++b) { acc[a][b][0]=0.f; acc[a][b][1]=0.f; acc[a][b][2]=0.f; acc[a][b][3]=0.f; }
    int grow[2], arw[2];
#pragma unroll
    for (int mt = 0; mt < 2; ++mt) {
        int m = e0 + (wm << 5) + (mt << 4) + r16;
        if (m >= E) m = E - 1;
        grow[mt] = src[m];
        arw[mt] = (wm << 5) + (mt << 4) + r16;
    }
#pragma unroll
    for (int kt = 0; kt < 8; ++kt) {
        short8 ah[2], al[2];
#pragma unroll
        for (int mt = 0; mt < 2; ++mt) {
            if (kt < 4) {
                unpack8(hpk + (size_t)grow[mt] * HD + (kt << 5) + (q << 3), ah[mt], al[mt]);
            } else {
                int row = arw[mt];
                int sh = (row & 7) << 2;
                int c = ((kt - 4) << 5) + (q << 3);
                uint4 w0 = *reinterpret_cast<const uint4*>(&elds[row * 128 + (c ^ sh)]);
                uint4 w1 = *reinterpret_cast<const uint4*>(&elds[row * 128 + ((c + 4) ^ sh)]);
                unsigned ww[8] = {w0.x, w0.y, w0.z, w0.w, w1.x, w1.y, w1.z, w1.w};
#pragma unroll
                for (int j = 0; j < 8; ++j) {
                    ah[mt][j] = (short)(ww[j] >> 16);
                    al[mt][j] = (short)(ww[j] & 0xffffu);
                }
            }
        }
        const int kg = (kt << 2) + q;
#pragma unroll
        for (int nt = 0; nt < 4; ++nt) {
            int nblk = (wn << 2) + nt;
            size_t boff = (((size_t)nblk * 32 + kg) * 16 + r16) * 8;
            short8 bh = *reinterpret_cast<const short8*>(Wehi + boff);
            short8 bl = *reinterpret_cast<const short8*>(Welo + boff);
#pragma unroll
            for (int mt = 0; mt < 2; ++mt) {
                acc[mt][nt] = __builtin_amdgcn_mfma_f32_16x16x32_bf16(ah[mt], bh, acc[mt][nt], 0, 0, 0);
                acc[mt][nt] = __builtin_amdgcn_mfma_f32_16x16x32_bf16(ah[mt], bl, acc[mt][nt], 0, 0, 0);
                acc[mt][nt] = __builtin_amdgcn_mfma_f32_16x16x32_bf16(al[mt], bh, acc[mt][nt], 0, 0, 0);
            }
        }
    }

    if (pass == 0) {
#pragma unroll
        for (int mt = 0; mt < 2; ++mt) {
            float pv[4] = {0.f, 0.f, 0.f, 0.f};
#pragma unroll
            for (int nt = 0; nt < 4; ++nt) {
                int col = (wn << 6) + (nt << 4) + r16;
                float bi = be[col], wc = wal[col];
#pragma unroll
                for (int i = 0; i < 4; ++i)
                    pv[i] += wc * lrelu_f(acc[mt][nt][i] + bi);
            }
#pragma unroll
            for (int i = 0; i < 4; ++i) {
                float p = pv[i];
                p += __shfl_xor(p, 1); p += __shfl_xor(p, 2);
                p += __shfl_xor(p, 4); p += __shfl_xor(p, 8);
                int m = e0 + (wm << 5) + (mt << 4) + (q << 2) + i;
                if (r16 == 0 && m < E) atomicAdd(&sc[m], p);
            }
        }
    } else {
#pragma unroll
        for (int mt = 0; mt < 2; ++mt)
#pragma unroll
            for (int i = 0; i < 4; ++i) {
                int m = e0 + (wm << 5) + (mt << 4) + (q << 2) + i;
                if (m >= E) continue;
                float a = sc[m];
                int dn = dst[m];
#pragma unroll
                for (int nt = 0; nt < 4; ++nt) {
                    int col = (wn << 6) + (nt << 4) + r16;
                    float v = lrelu_f(acc[mt][nt][i] + be[col]);
                    atomicAdd(&S[(size_t)dn * HD + col], a * v);
                }
            }
    }
}

// ---------------------------------------------------------------------------
// Fused GRU: out = relu(GRU(ctx, h)); ctx/h read packed u32.
// ghi/glo: 6 gate slices (ih_r, ih_z, ih_n, hh_r, hh_z, hh_n), stride SL.
// Block 64 rows x 64 cols, grid (ceil(M/64), 2).
// ---------------------------------------------------------------------------
#define GRU_SL (8 * 16 * 16 * 8)
__global__ __launch_bounds__(256) void gru_fused_kernel(
    const unsigned* __restrict__ ctxpk, const unsigned* __restrict__ hpk,
    const short* __restrict__ ghi, const short* __restrict__ glo,
    const float* __restrict__ bih, const float* __restrict__ bhh,
    float* __restrict__ out, int M)
{
    const int t = threadIdx.x, lane = t & 63, w = t >> 6;
    const int wm = w & 1, wn = w >> 1, q = lane >> 4, r16 = lane & 15;
    const int m0 = blockIdx.x * 64, j0 = blockIdx.y * 64;

    f32x4 acc[6][2][2];
#pragma unroll
    for (int g = 0; g < 6; ++g)
#pragma unroll
        for (int a = 0; a < 2; ++a)
#pragma unroll
            for (int b = 0; b < 2; ++b) { acc[g][a][b][0]=0.f; acc[g][a][b][1]=0.f; acc[g][a][b][2]=0.f; acc[g][a][b][3]=0.f; }

    int arow[2];
#pragma unroll
    for (int mt = 0; mt < 2; ++mt) {
        int m = m0 + (wm << 5) + (mt << 4) + r16;
        arow[mt] = (m >= M) ? M - 1 : m;
    }

    // ih gates (A = ctx)
#pragma unroll
    for (int kt = 0; kt < 4; ++kt) {
        short8 ah[2], al[2];
#pragma unroll
        for (int mt = 0; mt < 2; ++mt)
            unpack8(ctxpk + (size_t)arow[mt] * HD + (kt << 5) + (q << 3), ah[mt], al[mt]);
        const int kg = (kt << 2) + q;
#pragma unroll
        for (int g = 0; g < 3; ++g)
#pragma unroll
            for (int nt = 0; nt < 2; ++nt) {
                int nblk = (j0 >> 4) + (wn << 1) + nt;
                size_t boff = (size_t)g * GRU_SL + (((size_t)nblk * 16 + kg) * 16 + r16) * 8;
                short8 bh = *reinterpret_cast<const short8*>(ghi + boff);
                short8 bl = *reinterpret_cast<const short8*>(glo + boff);
#pragma unroll
                for (int mt = 0; mt < 2; ++mt) {
                    acc[g][mt][nt] = __builtin_amdgcn_mfma_f32_16x16x32_bf16(ah[mt], bh, acc[g][mt][nt], 0, 0, 0);
                    acc[g][mt][nt] = __builtin_amdgcn_mfma_f32_16x16x32_bf16(ah[mt], bl, acc[g][mt][nt], 0, 0, 0);
                    acc[g][mt][nt] = __builtin_amdgcn_mfma_f32_16x16x32_bf16(al[mt], bh, acc[g][mt][nt], 0, 0, 0);
                }
            }
    }
    // hh gates (A = h)
#pragma unroll
    for (int kt = 0; kt < 4; ++kt) {
        short8 ah[2], al[2];
#pragma unroll
        for (int mt = 0; mt < 2; ++mt)
            unpack8(hpk + (size_t)arow[mt] * HD + (kt << 5) + (q << 3), ah[mt], al[mt]);
        const int kg = (kt << 2) + q;
#pragma unroll
        for (int g = 3; g < 6; ++g)
#pragma unroll
            for (int nt = 0; nt < 2; ++nt) {
                int nblk = (j0 >> 4) + (wn << 1) + nt;
                size_t boff = (size_t)g * GRU_SL + (((size_t)nblk * 16 + kg) * 16 + r16) * 8;
                short8 bh = *reinterpret_cast<const short8*>(ghi + boff);
                short8 bl = *reinterpret_cast<const short8*>(glo + boff);
#pragma unroll
                for (int mt = 0; mt < 2; ++mt) {
                    acc[g][mt][nt] = __builtin_amdgcn_mfma_f32_16x16x32_bf16(ah[mt], bh, acc[g][mt][nt], 0, 0, 0);
                    acc[g][mt][nt] = __builtin_amdgcn_mfma_f32_16x16x32_bf16(ah[mt], bl, acc[g][mt][nt], 0, 0, 0);
                    acc[g][mt][nt] = __builtin_amdgcn_mfma_f32_16x16x32_bf16(al[mt], bh, acc[g][mt][nt], 0, 0, 0);
                }
            }
    }

#pragma unroll
    for (int mt = 0; mt < 2; ++mt)
#pragma unroll
        for (int nt = 0; nt < 2; ++nt) {
            int j = j0 + (wn << 5) + (nt << 4) + r16;
            float bir = bih[j], biz = bih[HD + j], bin = bih[2 * HD + j];
            float bhr = bhh[j], bhz = bhh[HD + j], bhn = bhh[2 * HD + j];
#pragma unroll
            for (int i = 0; i < 4; ++i) {
                int m = m0 + (wm << 5) + (mt << 4) + (q << 2) + i;
                if (m >= M) continue;
                float r = sigmoid_f(acc[0][mt][nt][i] + bir + acc[3][mt][nt][i] + bhr);
                float z = sigmoid_f(acc[1][mt][nt][i] + biz + acc[4][mt][nt][i] + bhz);
                float hn = acc[5][mt][nt][i] + bhn;
                float nn = tanhf(acc[2][mt][nt][i] + bin + r * hn);
                float hv = unpack_f32(hpk[(size_t)m * HD + j]);
                out[(size_t)m * HD + j] = fmaxf((1.f - z) * nn + z * hv, 0.f);
            }
        }
}

__global__ void init_maxsum_kernel(float* mx, float* sm, int n) {
    int i = blockIdx.x * blockDim.x + threadIdx.x;
    if (i < n) { mx[i] = -__builtin_inff(); sm[i] = 0.f; }
}

__global__ void score_combine_kernel(float* __restrict__ sc, const float* __restrict__ hd2,
                                     const int* __restrict__ seg, const float* __restrict__ bal,
                                     float* __restrict__ maxbuf, int count) {
    int i = blockIdx.x * blockDim.x + threadIdx.x;
    if (i >= count) return;
    int s = seg[i];
    float v = lrelu_f(sc[i] + hd2[s] + bal[0]);
    sc[i] = v;
    atomicMaxF(&maxbuf[s], v);
}

__global__ __launch_bounds__(256) void score_kernel(
    const float* __restrict__ A, const float* __restrict__ B,
    const int* __restrict__ seg, const float* __restrict__ w,
    const float* __restrict__ bal, float* __restrict__ out,
    float* __restrict__ maxbuf, int count)
{
    int i = (blockIdx.x * blockDim.x + threadIdx.x) >> 6;
    int lane = threadIdx.x & 63;
    if (i >= count) return;
    int s = seg[i];
    const float* ar = A + (size_t)i * HD;
    const float* br = B + (size_t)s * HD;
    float p = ar[lane] * w[lane] + ar[lane + 64] * w[lane + 64]
            + br[lane] * w[128 + lane] + br[lane + 64] * w[192 + lane];
#pragma unroll
    for (int off = 32; off > 0; off >>= 1) p += __shfl_down(p, off);
    if (lane == 0) {
        float v = lrelu_f(p + bal[0]);
        out[i] = v;
        atomicMaxF(&maxbuf[s], v);
    }
}

__global__ void expsum_kernel(float* __restrict__ sc, const float* __restrict__ mx,
                              float* __restrict__ sm, const int* __restrict__ seg, int count) {
    int i = blockIdx.x * blockDim.x + threadIdx.x;
    if (i >= count) return;
    int s = seg[i];
    float p = expf(sc[i] - mx[s]);
    sc[i] = p;
    atomicAdd(&sm[s], p);
}

__global__ void attdiv_kernel(float* __restrict__ sc, const float* __restrict__ sm,
                              const int* __restrict__ seg, int count) {
    int i = blockIdx.x * blockDim.x + threadIdx.x;
    if (i >= count) return;
    sc[i] = sc[i] / sm[seg[i]];
}

__global__ void gru_gate_kernel(const float* __restrict__ gi, const float* __restrict__ gh,
                                const float* __restrict__ h, float* __restrict__ out, int M) {
    size_t idx = (size_t)blockIdx.x * blockDim.x + threadIdx.x;
    if (idx >= (size_t)M * HD) return;
    size_t row = idx >> 7; int col = (int)(idx & 127);
    const float* gir = gi + row * H3;
    const float* ghr = gh + row * H3;
    float r = sigmoid_f(gir[col] + ghr[col]);
    float z = sigmoid_f(gir[col + 128] + ghr[col + 128]);
    float nn = tanhf(gir[col + 256] + r * ghr[col + 256]);
    float o = (1.f - z) * nn + z * h[idx];
    out[idx] = fmaxf(o, 0.f);
}

__global__ void lrelu_copy_kernel(const float* __restrict__ in, float* __restrict__ out, size_t n) {
    size_t i = (size_t)blockIdx.x * blockDim.x + threadIdx.x;
    if (i >= n) return;
    out[i] = lrelu_f(in[i]);
}

__global__ void segsum_kernel(const float* __restrict__ nb, const int* __restrict__ gid,
                              float* __restrict__ sn, int Nn) {
    size_t idx = (size_t)blockIdx.x * blockDim.x + threadIdx.x;
    if (idx >= (size_t)Nn * HD) return;
    size_t row = idx >> 7; int col = (int)(idx & 127);
    atomicAdd(&sn[(size_t)gid[row] * HD + col], nb[idx]);
}

__global__ void seg_scale_sum_kernel(const float* __restrict__ nb, const int* __restrict__ gid,
                                     const float* __restrict__ scale, float* __restrict__ out, int Nn) {
    size_t idx = (size_t)blockIdx.x * blockDim.x + threadIdx.x;
    if (idx >= (size_t)Nn * HD) return;
    size_t row = idx >> 7; int col = (int)(idx & 127);
    atomicAdd(&out[(size_t)gid[row] * HD + col], scale[row] * nb[idx]);
}

__global__ void final_kernel(const float* __restrict__ sn, const float* __restrict__ Wp,
                             const float* __restrict__ bp, float* __restrict__ out, int G) {
    int g = (blockIdx.x * blockDim.x + threadIdx.x) >> 6;
    int lane = threadIdx.x & 63;
    if (g >= G) return;
    const float* r = sn + (size_t)g * HD;
    float p = r[lane] * Wp[lane] + r[lane + 64] * Wp[lane + 64];
#pragma unroll
    for (int off = 32; off > 0; off >>= 1) p += __shfl_down(p, off);
    if (lane == 0) out[g] = p + bp[0];
}

__global__ void canary_kernel(float* out, int n) {
    int i = blockIdx.x * blockDim.x + threadIdx.x;
    if (i < n) out[i] = 123.456f;
}

struct PkB { const short* hi; const short* lo; int KG; };

extern "C" void kernel_launch(void* const* d_in, const int* in_sizes, int n_in,
                              void* d_out, int out_size, void* d_ws, size_t ws_size,
                              hipStream_t stream) {
    const float* node = (const float*)d_in[0];
    const float* edge = (const float*)d_in[1];
    const int*   src  = (const int*)d_in[2];
    const int*   dst  = (const int*)d_in[3];
    const int*   gid  = (const int*)d_in[4];
    const float* Wn0  = (const float*)d_in[5];
    const float* bn0  = (const float*)d_in[6];
    const float* We0  = (const float*)d_in[7];
    const float* be0  = (const float*)d_in[8];
    const float* aWn  = (const float*)d_in[9];
    const float* abn  = (const float*)d_in[10];
    const float* aWe  = (const float*)d_in[11];
    const float* abe  = (const float*)d_in[12];
    const float* aWal = (const float*)d_in[13];
    const float* abal = (const float*)d_in[14];
    const float* aWat = (const float*)d_in[15];
    const float* abat = (const float*)d_in[16];
    const float* aWih = (const float*)d_in[17];
    const float* abih = (const float*)d_in[18];
    const float* aWhh = (const float*)d_in[19];
    const float* abhh = (const float*)d_in[20];
    const float* mWal = (const float*)d_in[21];
    const float* mbal = (const float*)d_in[22];
    const float* mWat = (const float*)d_in[23];
    const float* mbat = (const float*)d_in[24];
    const float* mWih = (const float*)d_in[25];
    const float* mbih = (const float*)d_in[26];
    const float* mWhh = (const float*)d_in[27];
    const float* mbhh = (const float*)d_in[28];
    const float* Wp   = (const float*)d_in[29];
    const float* bp   = (const float*)d_in[30];

    const int N = in_sizes[0] / 64;
    const int E = in_sizes[1] / 16;
    const int G = out_size;
    const int D = in_sizes[9] / (HD * HD);
    const int L = in_sizes[21] / (2 * HD);
    if (D > 8 || L > 4) return;

    char* wsb = (char*)d_ws;

    // ---- weight pre-pack region ----
    short* pkcur = (short*)wsb;
    auto packB = [&](const float* B, int K, int ldb, int col0, int Ncols) -> PkB {
        int KG = 4 * ((K + 31) / 32);
        size_t elems = (size_t)(Ncols >> 4) * KG * 16 * 8;
        short* hi = pkcur; pkcur += elems;
        short* lo = pkcur; pkcur += elems;
        int total = (Ncols >> 4) * KG * 16;
        pack_b_kernel<<<(total + 255) / 256, 256, 0, stream>>>(B, K, ldb, col0, Ncols, hi, lo);
        PkB p; p.hi = hi; p.lo = lo; p.KG = KG; return p;
    };
    PkB pWn0 = packB(Wn0, 64, HD, 0, HD);
    PkB pWe0 = packB(We0, 16, HD, 0, HD);
    PkB pAWn[8], pAWe[8], pAWat[8];
    const short *gHi[8], *gLo[8];
    for (int d = 0; d < D; ++d) {
        pAWn[d]  = packB(aWn  + (size_t)d * HD * HD,     HD,     HD, 0, HD);
        pAWe[d]  = packB(aWe  + (size_t)d * 2 * HD * HD, 2 * HD, HD, 0, HD);
        pAWat[d] = packB(aWat + (size_t)d * HD * HD,     HD,     HD, 0, HD);
        short* ghi = pkcur; pkcur += 6 * GRU_SL;
        short* glo = pkcur; pkcur += 6 * GRU_SL;
        for (int g = 0; g < 3; ++g) {
            int total = (HD >> 4) * 16 * 16;
            pack_b_kernel<<<(total + 255) / 256, 256, 0, stream>>>(
                aWih + (size_t)d * HD * H3, HD, H3, g * HD, HD, ghi + g * GRU_SL, glo + g * GRU_SL);
            pack_b_kernel<<<(total + 255) / 256, 256, 0, stream>>>(
                aWhh + (size_t)d * HD * H3, HD, H3, g * HD, HD, ghi + (3 + g) * GRU_SL, glo + (3 + g) * GRU_SL);
        }
        gHi[d] = ghi; gLo[d] = glo;
    }
    PkB pMWat[4], pMWih[4], pMWhh[4];
    for (int l = 0; l < L; ++l) {
        pMWat[l] = packB(mWat + (size_t)l * HD * HD, HD, HD, 0, HD);
        pMWih[l] = packB(mWih + (size_t)l * HD * H3, HD, H3, 0, H3);
        pMWhh[l] = packB(mWhh + (size_t)l * HD * H3, HD, H3, 0, H3);
    }

    // ---- workspace ----
    size_t off = ((size_t)((char*)pkcur - wsb) + 255) & ~(size_t)255;
    auto alloc = [&](size_t bytes) -> void* {
        void* p = (void*)(wsb + off);
        off += (bytes + 255) & ~(size_t)255;
        return p;
    };
    float*    nbuf  = (float*)alloc((size_t)N * HD * 4);  // node state n / S scatter target
    unsigned* hpk   = (unsigned*)alloc((size_t)N * HD * 4);
    unsigned* ctxpk = (unsigned*)alloc((size_t)N * HD * 4);
    float* sc_e = (float*)alloc((size_t)E * 4);
    float* nmax = (float*)alloc((size_t)N * 4);
    float* nsum = (float*)alloc((size_t)N * 4);
    float* sc_n = (float*)alloc((size_t)N * 4);
    float* hd2  = (float*)alloc((size_t)N * 4);
    float* sn   = (float*)alloc((size_t)G * HD * 4);
    float* sbuf = (float*)alloc((size_t)G * HD * 4);
    float* sctx = (float*)alloc((size_t)G * HD * 4);
    float* Sg   = (float*)alloc((size_t)G * HD * 4);
    float* gim  = (float*)alloc((size_t)G * H3 * 4);
    float* ghm  = (float*)alloc((size_t)G * H3 * 4);
    float* gmax = (float*)alloc((size_t)G * 4);
    float* gsum = (float*)alloc((size_t)G * 4);
    if (off > ws_size) {
        canary_kernel<<<(G + 255) / 256, 256, 0, stream>>>((float*)d_out, G);
        return;
    }

    auto mgemm = [&](const float* A, int K, const PkB& pk, const float* bias, void* C,
                     int M, int Nc, int act, const float* rdw, float* rdout,
                     const float* rowmask, int outpk) {
        dim3 g((M + 63) / 64, Nc / 64);
        mfma_gemm<<<g, dim3(256), 0, stream>>>(A, K, pk.hi, pk.lo, pk.KG, bias, (float*)C,
                                               M, Nc, act, rdw, rdout, rowmask, outpk);
    };

    // ---- input embedding ----
    mgemm(node, 64, pWn0, bn0, nbuf, N, HD, 1, nullptr, nullptr, nullptr, 0);

    // ---- atom-level message passing ----
    const int EB = (E + 63) / 64;
    for (int d = 0; d < D; ++d) {
        const float* bn_d  = abn  + (size_t)d * HD;
        const float* be_d  = abe  + (size_t)d * HD;
        const float* Wal_d = aWal + (size_t)d * 2 * HD;
        const float* bal_d = abal + d;
        const float* bat_d = abat + (size_t)d * HD;
        const float* bih_d = abih + (size_t)d * H3;
        const float* bhh_d = abhh + (size_t)d * H3;

        hipMemsetAsync(hd2, 0, (size_t)N * 4, stream);
        hipMemsetAsync(sc_e, 0, (size_t)E * 4, stream);
        // h = lrelu(n @ Wn + bn) -> packed; rowdot hd2 = h . Wal[128:256]
        mgemm(nbuf, HD, pAWn[d], bn_d, hpk, N, HD, 1, Wal_d + HD, hd2, nullptr, 1);
        init_maxsum_kernel<<<(N + 255) / 256, 256, 0, stream>>>(nmax, nsum, N);
        // pass A: sc_e = msg . Wal[0:128]
        msg_pass_kernel<<<EB, 256, 0, stream>>>(hpk, src, dst, edge, pWe0.hi, pWe0.lo, be0,
                                                pAWe[d].hi, pAWe[d].lo, be_d, Wal_d,
                                                sc_e, nullptr, E, 0);
        score_combine_kernel<<<(E + 255) / 256, 256, 0, stream>>>(sc_e, hd2, dst, bal_d, nmax, E);
        expsum_kernel<<<(E + 255) / 256, 256, 0, stream>>>(sc_e, nmax, nsum, dst, E);
        attdiv_kernel<<<(E + 255) / 256, 256, 0, stream>>>(sc_e, nsum, dst, E);
        // pass B: S (= nbuf) = segsum(att * msg)
        hipMemsetAsync(nbuf, 0, (size_t)N * HD * 4, stream);
        msg_pass_kernel<<<EB, 256, 0, stream>>>(hpk, src, dst, edge, pWe0.hi, pWe0.lo, be0,
                                                pAWe[d].hi, pAWe[d].lo, be_d, nullptr,
                                                sc_e, nbuf, E, 1);
        // ctx = elu(S @ Wat + bat) -> packed; empty-dst rows (nsum==0) -> 0
        mgemm(nbuf, HD, pAWat[d], bat_d, ctxpk, N, HD, 3, nullptr, nullptr, nsum, 1);
        // n = relu(GRU(ctx, h)) -> nbuf
        dim3 gg((N + 63) / 64, 2);
        gru_fused_kernel<<<gg, dim3(256), 0, stream>>>(ctxpk, hpk, gHi[d], gLo[d],
                                                       bih_d, bhh_d, nbuf, N);
    }

    // ---- molecule-level readout ----
    hipMemsetAsync(sn, 0, (size_t)G * HD * 4, stream);
    segsum_kernel<<<((size_t)N * HD + 255) / 256, 256, 0, stream>>>(nbuf, gid, sn, N);
    for (int l = 0; l < L; ++l) {
        const float* Wal_l = mWal + (size_t)l * 2 * HD;
        const float* bal_l = mbal + l;
        const float* bat_l = mbat + (size_t)l * HD;
        const float* bih_l = mbih + (size_t)l * H3;
        const float* bhh_l = mbhh + (size_t)l * H3;

        lrelu_copy_kernel<<<((size_t)G * HD + 255) / 256, 256, 0, stream>>>(sn, sbuf, (size_t)G * HD);
        init_maxsum_kernel<<<(G + 255) / 256, 256, 0, stream>>>(gmax, gsum, G);
        score_kernel<<<(N + 3) / 4, 256, 0, stream>>>(nbuf, sbuf, gid, Wal_l, bal_l, sc_n, gmax, N);
        expsum_kernel<<<(N + 255) / 256, 256, 0, stream>>>(sc_n, gmax, gsum, gid, N);
        attdiv_kernel<<<(N + 255) / 256, 256, 0, stream>>>(sc_n, gsum, gid, N);
        hipMemsetAsync(Sg, 0, (size_t)G * HD * 4, stream);
        seg_scale_sum_kernel<<<((size_t)N * HD + 255) / 256, 256, 0, stream>>>(nbuf, gid, sc_n, Sg, N);
        mgemm(Sg, HD, pMWat[l], bat_l, sctx, G, HD, 3, nullptr, nullptr, gsum, 0);
        mgemm(sctx, HD, pMWih[l], bih_l, gim, G, H3, 0, nullptr, nullptr, nullptr, 0);
        mgemm(sbuf, HD, pMWhh[l], bhh_l, ghm, G, H3, 0, nullptr, nullptr, nullptr, 0);
        gru_gate_kernel<<<((size_t)G * HD + 255) / 256, 256, 0, stream>>>(gim, ghm, sbuf, sn, G);
    }

    // ---- final prediction ----
    final_kernel<<<(G + 3) / 4, 256, 0, stream>>>(sn, Wp, bp, (float*)d_out, G);
}

// Round 12
// 2107.894 us; speedup vs baseline: 1.2010x; 1.2010x over previous
//
#include <hip/hip_runtime.h>
#include <hip/hip_bf16.h>
#include <math.h>

// AttentiveFP forward. Split-bf16 (3-term) MFMA engine.
//  - CSR-by-dst (built once): pass A stores msg at CSR slot; ctx = per-node
//    contiguous gather (no atomics, no recompute). Tiered msg storage
//    (u32-packed / bf16 / fallback to atomic-scatter recompute) with
//    lifetime-overlaid workspace (msgpk | ctxpk | mol buffers share OVR).
//  - activations packed u32 (bf16 hi|lo); fused edge kernel; sum(att)=1
//    Wat move (+ empty-segment rowmask); fused GRU
// H=128, 3H=384.

#define HD 128
#define H3 384

typedef __attribute__((ext_vector_type(8))) short short8;
typedef __attribute__((ext_vector_type(4))) float f32x4;

__device__ __forceinline__ float lrelu_f(float x) { return x > 0.f ? x : 0.01f * x; }
__device__ __forceinline__ float sigmoid_f(float x) { return 1.f / (1.f + expf(-x)); }

__device__ __forceinline__ void atomicMaxF(float* addr, float val) {
    int iv = __float_as_int(val);
    if (iv >= 0) atomicMax((int*)addr, iv);
    else atomicMin((unsigned int*)addr, (unsigned int)iv);
}

__device__ __forceinline__ unsigned short bf16_rne(float v, float* back) {
    unsigned u = __float_as_uint(v);
    unsigned r = (u + 0x7FFFu + ((u >> 16) & 1u)) >> 16;
    *back = __uint_as_float(r << 16);
    return (unsigned short)r;
}

__device__ __forceinline__ unsigned pack_hl(float v) {
    float back, d;
    unsigned short h = bf16_rne(v, &back);
    unsigned short l = bf16_rne(v - back, &d);
    return ((unsigned)h << 16) | (unsigned)l;
}
__device__ __forceinline__ float unpack_f32(unsigned w) {
    return __uint_as_float(w & 0xffff0000u) + __uint_as_float(w << 16);
}

__device__ __forceinline__ void split8(const float* p, short8& h8, short8& l8) {
    float4 u0 = *reinterpret_cast<const float4*>(p);
    float4 u1 = *reinterpret_cast<const float4*>(p + 4);
    float vv[8] = {u0.x, u0.y, u0.z, u0.w, u1.x, u1.y, u1.z, u1.w};
#pragma unroll
    for (int j = 0; j < 8; ++j) {
        float back, d;
        h8[j] = (short)bf16_rne(vv[j], &back);
        l8[j] = (short)bf16_rne(vv[j] - back, &d);
    }
}

__device__ __forceinline__ void unpack8(const unsigned* p, short8& h8, short8& l8) {
    uint4 w0 = *reinterpret_cast<const uint4*>(p);
    uint4 w1 = *reinterpret_cast<const uint4*>(p + 4);
    unsigned ww[8] = {w0.x, w0.y, w0.z, w0.w, w1.x, w1.y, w1.z, w1.w};
#pragma unroll
    for (int j = 0; j < 8; ++j) {
        h8[j] = (short)(ww[j] >> 16);
        l8[j] = (short)(ww[j] & 0xffffu);
    }
}

// ---------------------------------------------------------------------------
__global__ void pack_b_kernel(const float* __restrict__ B, int K, int ldb, int col0,
                              int Ncols, short* __restrict__ hi, short* __restrict__ lo) {
    int KG = 4 * ((K + 31) / 32);
    int idx = blockIdx.x * blockDim.x + threadIdx.x;
    int total = (Ncols >> 4) * KG * 16;
    if (idx >= total) return;
    int col = idx & 15;
    int kg = (idx >> 4) % KG;
    int nblk = idx / (16 * KG);
    size_t o = (size_t)idx * 8;
#pragma unroll
    for (int e = 0; e < 8; ++e) {
        int k = kg * 8 + e;
        float v = (k < K) ? B[(size_t)k * ldb + col0 + nblk * 16 + col] : 0.f;
        float hf, d;
        unsigned short h = bf16_rne(v, &hf);
        unsigned short l = bf16_rne(v - hf, &d);
        hi[o + e] = (short)h;
        lo[o + e] = (short)l;
    }
}

// ---------------------------------------------------------------------------
// Generic split-bf16 GEMM.
// ---------------------------------------------------------------------------
__global__ __launch_bounds__(256) void mfma_gemm(
    const float* __restrict__ A, int K,
    const short* __restrict__ Bhi, const short* __restrict__ Blo, int KG,
    const float* __restrict__ bias, float* __restrict__ C, int M, int N, int act,
    const float* __restrict__ rdw, float* __restrict__ rdout,
    const float* __restrict__ rowmask, int outpk)
{
    const int t = threadIdx.x, lane = t & 63, w = t >> 6;
    const int wm = w & 1, wn = w >> 1, q = lane >> 4, r16 = lane & 15;
    const int m0 = blockIdx.x * 64, n0 = blockIdx.y * 64;
    const int KT = K >> 5;

    f32x4 acc[2][2];
#pragma unroll
    for (int a = 0; a < 2; ++a)
#pragma unroll
        for (int b = 0; b < 2; ++b) { acc[a][b][0]=0.f; acc[a][b][1]=0.f; acc[a][b][2]=0.f; acc[a][b][3]=0.f; }

    int arow[2];
#pragma unroll
    for (int mt = 0; mt < 2; ++mt) {
        int m = m0 + (wm << 5) + (mt << 4) + r16;
        arow[mt] = (m >= M) ? M - 1 : m;
    }

    for (int kt = 0; kt < KT; ++kt) {
        short8 ah[2], al[2];
#pragma unroll
        for (int mt = 0; mt < 2; ++mt)
            split8(A + (size_t)arow[mt] * K + (kt << 5) + (q << 3), ah[mt], al[mt]);
        const int kg = (kt << 2) + q;
#pragma unroll
        for (int nt = 0; nt < 2; ++nt) {
            int nblk = (n0 >> 4) + (wn << 1) + nt;
            size_t boff = (((size_t)nblk * KG + kg) * 16 + r16) * 8;
            short8 bh = *reinterpret_cast<const short8*>(Bhi + boff);
            short8 bl = *reinterpret_cast<const short8*>(Blo + boff);
#pragma unroll
            for (int mt = 0; mt < 2; ++mt) {
                acc[mt][nt] = __builtin_amdgcn_mfma_f32_16x16x32_bf16(ah[mt], bh, acc[mt][nt], 0, 0, 0);
                acc[mt][nt] = __builtin_amdgcn_mfma_f32_16x16x32_bf16(ah[mt], bl, acc[mt][nt], 0, 0, 0);
                acc[mt][nt] = __builtin_amdgcn_mfma_f32_16x16x32_bf16(al[mt], bh, acc[mt][nt], 0, 0, 0);
            }
        }
    }

#pragma unroll
    for (int mt = 0; mt < 2; ++mt) {
        float pv[4] = {0.f, 0.f, 0.f, 0.f};
#pragma unroll
        for (int nt = 0; nt < 2; ++nt) {
            int col = n0 + (wn << 5) + (nt << 4) + r16;
            float bi = bias ? bias[col] : 0.f;
            float wc = rdw ? rdw[col] : 0.f;
#pragma unroll
            for (int i = 0; i < 4; ++i) {
                int m = m0 + (wm << 5) + (mt << 4) + (q << 2) + i;
                float v = acc[mt][nt][i] + bi;
                if (act == 1) v = v > 0.f ? v : 0.01f * v;
                else if (act == 2) v = fmaxf(v, 0.f);
                else if (act == 3) v = v > 0.f ? v : expf(v) - 1.f;
                if (rowmask && m < M && rowmask[m] == 0.f) v = 0.f;
                pv[i] += wc * v;
                if (m < M) {
                    if (outpk) ((unsigned*)C)[(size_t)m * N + col] = pack_hl(v);
                    else C[(size_t)m * N + col] = v;
                }
            }
        }
        if (rdw) {
#pragma unroll
            for (int i = 0; i < 4; ++i) {
                float p = pv[i];
                p += __shfl_xor(p, 1); p += __shfl_xor(p, 2);
                p += __shfl_xor(p, 4); p += __shfl_xor(p, 8);
                int m = m0 + (wm << 5) + (mt << 4) + (q << 2) + i;
                if (r16 == 0 && m < M) atomicAdd(&rdout[m], p);
            }
        }
    }
}

// ---------------------------------------------------------------------------
// Fused edge kernel. e computed on the fly (LDS). msg = lrelu([h[src],e]@We+be).
// mode 0: rowdot score + store msg (packed per fullprec) at CSR slot ipos[m]
// mode 1: rowdot score only (fallback pass A)
// mode 2: scatter S[dst[m]] += sc[m] * msg (fallback pass B)
// ---------------------------------------------------------------------------
__global__ __launch_bounds__(256) void msg_pass_kernel(
    const unsigned* __restrict__ hpk, const int* __restrict__ src,
    const int* __restrict__ dst,
    const float* __restrict__ edge,
    const short* __restrict__ W0hi, const short* __restrict__ W0lo,
    const float* __restrict__ be0,
    const short* __restrict__ Wehi, const short* __restrict__ Welo,
    const float* __restrict__ be,
    const float* __restrict__ wal,
    float* __restrict__ sc, float* __restrict__ S,
    const int* __restrict__ ipos, void* __restrict__ msgpk, int fullprec,
    int E, int mode)
{
    __shared__ unsigned int elds[64 * 128];
    const int t = threadIdx.x, lane = t & 63, w = t >> 6;
    const int wm = w & 1, wn = w >> 1, q = lane >> 4, r16 = lane & 15;
    const int e0 = blockIdx.x * 64;

    // ---- stage 1: e tile ----
    {
        f32x4 ea[2][4];
#pragma unroll
        for (int a = 0; a < 2; ++a)
#pragma unroll
            for (int b = 0; b < 4; ++b) { ea[a][b][0]=0.f; ea[a][b][1]=0.f; ea[a][b][2]=0.f; ea[a][b][3]=0.f; }
        short8 eah[2], eal[2];
#pragma unroll
        for (int mt = 0; mt < 2; ++mt) {
            int er = e0 + (wm << 5) + (mt << 4) + r16;
            if (er >= E) er = E - 1;
            if (q < 2) split8(edge + (size_t)er * 16 + (q << 3), eah[mt], eal[mt]);
            else {
#pragma unroll
                for (int j = 0; j < 8; ++j) { eah[mt][j] = 0; eal[mt][j] = 0; }
            }
        }
#pragma unroll
        for (int nt = 0; nt < 4; ++nt) {
            int nblk = (wn << 2) + nt;
            size_t boff = (((size_t)nblk * 4 + q) * 16 + r16) * 8;
            short8 bh = *reinterpret_cast<const short8*>(W0hi + boff);
            short8 bl = *reinterpret_cast<const short8*>(W0lo + boff);
#pragma unroll
            for (int mt = 0; mt < 2; ++mt) {
                ea[mt][nt] = __builtin_amdgcn_mfma_f32_16x16x32_bf16(eah[mt], bh, ea[mt][nt], 0, 0, 0);
                ea[mt][nt] = __builtin_amdgcn_mfma_f32_16x16x32_bf16(eah[mt], bl, ea[mt][nt], 0, 0, 0);
                ea[mt][nt] = __builtin_amdgcn_mfma_f32_16x16x32_bf16(eal[mt], bh, ea[mt][nt], 0, 0, 0);
            }
        }
#pragma unroll
        for (int mt = 0; mt < 2; ++mt)
#pragma unroll
            for (int nt = 0; nt < 4; ++nt) {
                int col = (wn << 6) + (nt << 4) + r16;
#pragma unroll
                for (int i = 0; i < 4; ++i) {
                    int row = (wm << 5) + (mt << 4) + (q << 2) + i;
                    float v = lrelu_f(ea[mt][nt][i] + be0[col]);
                    elds[row * 128 + (col ^ ((row & 7) << 2))] = pack_hl(v);
                }
            }
    }
    __syncthreads();

    // ---- stage 2: msg ----
    f32x4 acc[2][4];
#pragma unroll
    for (int a = 0; a < 2; ++a)
#pragma unroll
        for (int b = 0; b < 4; ++b) { acc[a][b][0]=0.f; acc[a][b][1]=0.f; acc[a][b][2]=0.f; acc[a][b][3]=0.f; }
    int grow[2], arw[2];
#pragma unroll
    for (int mt = 0; mt < 2; ++mt) {
        int m = e0 + (wm << 5) + (mt << 4) + r16;
        if (m >= E) m = E - 1;
        grow[mt] = src[m];
        arw[mt] = (wm << 5) + (mt << 4) + r16;
    }
#pragma unroll
    for (int kt = 0; kt < 8; ++kt) {
        short8 ah[2], al[2];
#pragma unroll
        for (int mt = 0; mt < 2; ++mt) {
            if (kt < 4) {
                unpack8(hpk + (size_t)grow[mt] * HD + (kt << 5) + (q << 3), ah[mt], al[mt]);
            } else {
                int row = arw[mt];
                int sh = (row & 7) << 2;
                int c = ((kt - 4) << 5) + (q << 3);
                uint4 w0 = *reinterpret_cast<const uint4*>(&elds[row * 128 + (c ^ sh)]);
                uint4 w1 = *reinterpret_cast<const uint4*>(&elds[row * 128 + ((c + 4) ^ sh)]);
                unsigned ww[8] = {w0.x, w0.y, w0.z, w0.w, w1.x, w1.y, w1.z, w1.w};
#pragma unroll
                for (int j = 0; j < 8; ++j) {
                    ah[mt][j] = (short)(ww[j] >> 16);
                    al[mt][j] = (short)(ww[j] & 0xffffu);
                }
            }
        }
        const int kg = (kt << 2) + q;
#pragma unroll
        for (int nt = 0; nt < 4; ++nt) {
            int nblk = (wn << 2) + nt;
            size_t boff = (((size_t)nblk * 32 + kg) * 16 + r16) * 8;
            short8 bh = *reinterpret_cast<const short8*>(Wehi + boff);
            short8 bl = *reinterpret_cast<const short8*>(Welo + boff);
#pragma unroll
            for (int mt = 0; mt < 2; ++mt) {
                acc[mt][nt] = __builtin_amdgcn_mfma_f32_16x16x32_bf16(ah[mt], bh, acc[mt][nt], 0, 0, 0);
                acc[mt][nt] = __builtin_amdgcn_mfma_f32_16x16x32_bf16(ah[mt], bl, acc[mt][nt], 0, 0, 0);
                acc[mt][nt] = __builtin_amdgcn_mfma_f32_16x16x32_bf16(al[mt], bh, acc[mt][nt], 0, 0, 0);
            }
        }
    }

    if (mode == 2) {
#pragma unroll
        for (int mt = 0; mt < 2; ++mt)
#pragma unroll
            for (int i = 0; i < 4; ++i) {
                int m = e0 + (wm << 5) + (mt << 4) + (q << 2) + i;
                if (m >= E) continue;
                float a = sc[m];
                int dn = dst[m];
#pragma unroll
                for (int nt = 0; nt < 4; ++nt) {
                    int col = (wn << 6) + (nt << 4) + r16;
                    float v = lrelu_f(acc[mt][nt][i] + be[col]);
                    atomicAdd(&S[(size_t)dn * HD + col], a * v);
                }
            }
        return;
    }

    // mode 0/1: rowdot score (+ CSR store in mode 0)
#pragma unroll
    for (int mt = 0; mt < 2; ++mt) {
        float pv[4] = {0.f, 0.f, 0.f, 0.f};
#pragma unroll
        for (int i = 0; i < 4; ++i) {
            int m = e0 + (wm << 5) + (mt << 4) + (q << 2) + i;
            int ip = (mode == 0 && m < E) ? ipos[m] : 0;
#pragma unroll
            for (int nt = 0; nt < 4; ++nt) {
                int col = (wn << 6) + (nt << 4) + r16;
                float v = lrelu_f(acc[mt][nt][i] + be[col]);
                pv[i] += wal[col] * v;
                if (mode == 0 && m < E) {
                    size_t ro = (size_t)ip * HD + col;
                    if (fullprec) ((unsigned*)msgpk)[ro] = pack_hl(v);
                    else { float b_; ((unsigned short*)msgpk)[ro] = bf16_rne(v, &b_); }
                }
            }
        }
#pragma unroll
        for (int i = 0; i < 4; ++i) {
            float p = pv[i];
            p += __shfl_xor(p, 1); p += __shfl_xor(p, 2);
            p += __shfl_xor(p, 4); p += __shfl_xor(p, 8);
            int m = e0 + (wm << 5) + (mt << 4) + (q << 2) + i;
            if (r16 == 0 && m < E) atomicAdd(&sc[m], p);
        }
    }
}

// ---------------------------------------------------------------------------
// ctx gather: one wave per node; msg rows contiguous per node (CSR order).
// ---------------------------------------------------------------------------
__global__ __launch_bounds__(256) void ctx_gather_kernel(
    const void* __restrict__ msgpk, const float* __restrict__ sc,
    const int* __restrict__ csr, const int* __restrict__ rowptr,
    float* __restrict__ S, int Nn, int fullprec)
{
    int wid = (blockIdx.x * blockDim.x + threadIdx.x) >> 6;
    int lane = threadIdx.x & 63;
    if (wid >= Nn) return;
    int p0 = rowptr[wid], p1 = rowptr[wid + 1];
    float a0 = 0.f, a1 = 0.f;
    if (fullprec) {
        const unsigned* mp = (const unsigned*)msgpk;
        for (int p = p0; p < p1; ++p) {
            float a = sc[csr[p]];
            uint2 w = *reinterpret_cast<const uint2*>(mp + (size_t)p * HD + lane * 2);
            a0 += a * unpack_f32(w.x);
            a1 += a * unpack_f32(w.y);
        }
    } else {
        const unsigned short* mp = (const unsigned short*)msgpk;
        for (int p = p0; p < p1; ++p) {
            float a = sc[csr[p]];
            unsigned w = *reinterpret_cast<const unsigned*>(mp + (size_t)p * HD + lane * 2);
            a0 += a * __uint_as_float(w << 16);
            a1 += a * __uint_as_float(w & 0xffff0000u);
        }
    }
    S[(size_t)wid * HD + lane * 2] = a0;
    S[(size_t)wid * HD + lane * 2 + 1] = a1;
}

// ---- CSR build: histogram + 3-kernel exclusive scan + fill ----
__global__ void hist_kernel(const int* __restrict__ dst, int* __restrict__ cnt, int E) {
    int i = blockIdx.x * blockDim.x + threadIdx.x;
    if (i < E) atomicAdd(&cnt[dst[i]], 1);
}
__global__ void scan1_kernel(const int* __restrict__ cnt, int* __restrict__ pre,
                             int* __restrict__ btot, int total) {
    __shared__ int ts[256];
    int base = blockIdx.x * 1024;
    int c[4], tsum = 0;
#pragma unroll
    for (int j = 0; j < 4; ++j) {
        int idx = base + threadIdx.x * 4 + j;
        c[j] = (idx < total) ? cnt[idx] : 0;
        tsum += c[j];
    }
    ts[threadIdx.x] = tsum;
    __syncthreads();
    for (int off = 1; off < 256; off <<= 1) {
        int v = (threadIdx.x >= off) ? ts[threadIdx.x - off] : 0;
        __syncthreads();
        ts[threadIdx.x] += v;
        __syncthreads();
    }
    int run = ts[threadIdx.x] - tsum;
#pragma unroll
    for (int j = 0; j < 4; ++j) {
        int idx = base + threadIdx.x * 4 + j;
        if (idx < total) pre[idx] = run;
        run += c[j];
    }
    if (threadIdx.x == 255) btot[blockIdx.x] = ts[255];
}
__global__ void scan2_kernel(int* __restrict__ btot, int nb) {
    __shared__ int ts[256];
    int v = (threadIdx.x < nb) ? btot[threadIdx.x] : 0;
    ts[threadIdx.x] = v;
    __syncthreads();
    for (int off = 1; off < 256; off <<= 1) {
        int u = (threadIdx.x >= off) ? ts[threadIdx.x - off] : 0;
        __syncthreads();
        ts[threadIdx.x] += u;
        __syncthreads();
    }
    if (threadIdx.x < nb) btot[threadIdx.x] = ts[threadIdx.x] - v;
}
__global__ void scan3_kernel(int* __restrict__ pre, const int* __restrict__ btot, int total) {
    int i = blockIdx.x * blockDim.x + threadIdx.x;
    if (i < total) pre[i] += btot[i >> 10];
}
__global__ void fill_kernel(const int* __restrict__ dst, const int* __restrict__ rowptr,
                            int* __restrict__ fillc, int* __restrict__ csr,
                            int* __restrict__ ipos, int E) {
    int i = blockIdx.x * blockDim.x + threadIdx.x;
    if (i >= E) return;
    int d = dst[i];
    int pos = rowptr[d] + atomicAdd(&fillc[d], 1);
    csr[pos] = i;
    ipos[i] = pos;
}

// ---------------------------------------------------------------------------
#define GRU_SL (8 * 16 * 16 * 8)
__global__ __launch_bounds__(256) void gru_fused_kernel(
    const unsigned* __restrict__ ctxpk, const unsigned* __restrict__ hpk,
    const short* __restrict__ ghi, const short* __restrict__ glo,
    const float* __restrict__ bih, const float* __restrict__ bhh,
    float* __restrict__ out, int M)
{
    const int t = threadIdx.x, lane = t & 63, w = t >> 6;
    const int wm = w & 1, wn = w >> 1, q = lane >> 4, r16 = lane & 15;
    const int m0 = blockIdx.x * 64, j0 = blockIdx.y * 64;

    f32x4 acc[6][2][2];
#pragma unroll
    for (int g = 0; g < 6; ++g)
#pragma unroll
        for (int a = 0; a < 2; ++a)
#pragma unroll
            for (int b = 0; b < 2; ++b) { acc[g][a][b][0]=0.f; acc[g][a][b][1]=0.f; acc[g][a][b][2]=0.f; acc[g][a][b][3]=0.f; }

    int arow[2];
#pragma unroll
    for (int mt = 0; mt < 2; ++mt) {
        int m = m0 + (wm << 5) + (mt << 4) + r16;
        arow[mt] = (m >= M) ? M - 1 : m;
    }

#pragma unroll
    for (int kt = 0; kt < 4; ++kt) {
        short8 ah[2], al[2];
#pragma unroll
        for (int mt = 0; mt < 2; ++mt)
            unpack8(ctxpk + (size_t)arow[mt] * HD + (kt << 5) + (q << 3), ah[mt], al[mt]);
        const int kg = (kt << 2) + q;
#pragma unroll
        for (int g = 0; g < 3; ++g)
#pragma unroll
            for (int nt = 0; nt < 2; ++nt) {
                int nblk = (j0 >> 4) + (wn << 1) + nt;
                size_t boff = (size_t)g * GRU_SL + (((size_t)nblk * 16 + kg) * 16 + r16) * 8;
                short8 bh = *reinterpret_cast<const short8*>(ghi + boff);
                short8 bl = *reinterpret_cast<const short8*>(glo + boff);
#pragma unroll
                for (int mt = 0; mt < 2; ++mt) {
                    acc[g][mt][nt] = __builtin_amdgcn_mfma_f32_16x16x32_bf16(ah[mt], bh, acc[g][mt][nt], 0, 0, 0);
                    acc[g][mt][nt] = __builtin_amdgcn_mfma_f32_16x16x32_bf16(ah[mt], bl, acc[g][mt][nt], 0, 0, 0);
                    acc[g][mt][nt] = __builtin_amdgcn_mfma_f32_16x16x32_bf16(al[mt], bh, acc[g][mt][nt], 0, 0, 0);
                }
            }
    }
#pragma unroll
    for (int kt = 0; kt < 4; ++kt) {
        short8 ah[2], al[2];
#pragma unroll
        for (int mt = 0; mt < 2; ++mt)
            unpack8(hpk + (size_t)arow[mt] * HD + (kt << 5) + (q << 3), ah[mt], al[mt]);
        const int kg = (kt << 2) + q;
#pragma unroll
        for (int g = 3; g < 6; ++g)
#pragma unroll
            for (int nt = 0; nt < 2; ++nt) {
                int nblk = (j0 >> 4) + (wn << 1) + nt;
                size_t boff = (size_t)g * GRU_SL + (((size_t)nblk * 16 + kg) * 16 + r16) * 8;
                short8 bh = *reinterpret_cast<const short8*>(ghi + boff);
                short8 bl = *reinterpret_cast<const short8*>(glo + boff);
#pragma unroll
                for (int mt = 0; mt < 2; ++mt) {
                    acc[g][mt][nt] = __builtin_amdgcn_mfma_f32_16x16x32_bf16(ah[mt], bh, acc[g][mt][nt], 0, 0, 0);
                    acc[g][mt][nt] = __builtin_amdgcn_mfma_f32_16x16x32_bf16(ah[mt], bl, acc[g][mt][nt], 0, 0, 0);
                    acc[g][mt][nt] = __builtin_amdgcn_mfma_f32_16x16x32_bf16(al[mt], bh, acc[g][mt][nt], 0, 0, 0);
                }
            }
    }

#pragma unroll
    for (int mt = 0; mt < 2; ++mt)
#pragma unroll
        for (int nt = 0; nt < 2; ++nt) {
            int j = j0 + (wn << 5) + (nt << 4) + r16;
            float bir = bih[j], biz = bih[HD + j], bin = bih[2 * HD + j];
            float bhr = bhh[j], bhz = bhh[HD + j], bhn = bhh[2 * HD + j];
#pragma unroll
            for (int i = 0; i < 4; ++i) {
                int m = m0 + (wm << 5) + (mt << 4) + (q << 2) + i;
                if (m >= M) continue;
                float r = sigmoid_f(acc[0][mt][nt][i] + bir + acc[3][mt][nt][i] + bhr);
                float z = sigmoid_f(acc[1][mt][nt][i] + biz + acc[4][mt][nt][i] + bhz);
                float hn = acc[5][mt][nt][i] + bhn;
                float nn = tanhf(acc[2][mt][nt][i] + bin + r * hn);
                float hv = unpack_f32(hpk[(size_t)m * HD + j]);
                out[(size_t)m * HD + j] = fmaxf((1.f - z) * nn + z * hv, 0.f);
            }
        }
}

__global__ void init_maxsum_kernel(float* mx, float* sm, int n) {
    int i = blockIdx.x * blockDim.x + threadIdx.x;
    if (i < n) { mx[i] = -__builtin_inff(); sm[i] = 0.f; }
}

__global__ void score_combine_kernel(float* __restrict__ sc, const float* __restrict__ hd2,
                                     const int* __restrict__ seg, const float* __restrict__ bal,
                                     float* __restrict__ maxbuf, int count) {
    int i = blockIdx.x * blockDim.x + threadIdx.x;
    if (i >= count) return;
    int s = seg[i];
    float v = lrelu_f(sc[i] + hd2[s] + bal[0]);
    sc[i] = v;
    atomicMaxF(&maxbuf[s], v);
}

__global__ __launch_bounds__(256) void score_kernel(
    const float* __restrict__ A, const float* __restrict__ B,
    const int* __restrict__ seg, const float* __restrict__ w,
    const float* __restrict__ bal, float* __restrict__ out,
    float* __restrict__ maxbuf, int count)
{
    int i = (blockIdx.x * blockDim.x + threadIdx.x) >> 6;
    int lane = threadIdx.x & 63;
    if (i >= count) return;
    int s = seg[i];
    const float* ar = A + (size_t)i * HD;
    const float* br = B + (size_t)s * HD;
    float p = ar[lane] * w[lane] + ar[lane + 64] * w[lane + 64]
            + br[lane] * w[128 + lane] + br[lane + 64] * w[192 + lane];
#pragma unroll
    for (int off = 32; off > 0; off >>= 1) p += __shfl_down(p, off);
    if (lane == 0) {
        float v = lrelu_f(p + bal[0]);
        out[i] = v;
        atomicMaxF(&maxbuf[s], v);
    }
}

__global__ void expsum_kernel(float* __restrict__ sc, const float* __restrict__ mx,
                              float* __restrict__ sm, const int* __restrict__ seg, int count) {
    int i = blockIdx.x * blockDim.x + threadIdx.x;
    if (i >= count) return;
    int s = seg[i];
    float p = expf(sc[i] - mx[s]);
    sc[i] = p;
    atomicAdd(&sm[s], p);
}

__global__ void attdiv_kernel(float* __restrict__ sc, const float* __restrict__ sm,
                              const int* __restrict__ seg, int count) {
    int i = blockIdx.x * blockDim.x + threadIdx.x;
    if (i >= count) return;
    sc[i] = sc[i] / sm[seg[i]];
}

__global__ void gru_gate_kernel(const float* __restrict__ gi, const float* __restrict__ gh,
                                const float* __restrict__ h, float* __restrict__ out, int M) {
    size_t idx = (size_t)blockIdx.x * blockDim.x + threadIdx.x;
    if (idx >= (size_t)M * HD) return;
    size_t row = idx >> 7; int col = (int)(idx & 127);
    const float* gir = gi + row * H3;
    const float* ghr = gh + row * H3;
    float r = sigmoid_f(gir[col] + ghr[col]);
    float z = sigmoid_f(gir[col + 128] + ghr[col + 128]);
    float nn = tanhf(gir[col + 256] + r * ghr[col + 256]);
    float o = (1.f - z) * nn + z * h[idx];
    out[idx] = fmaxf(o, 0.f);
}

__global__ void lrelu_copy_kernel(const float* __restrict__ in, float* __restrict__ out, size_t n) {
    size_t i = (size_t)blockIdx.x * blockDim.x + threadIdx.x;
    if (i >= n) return;
    out[i] = lrelu_f(in[i]);
}

__global__ void segsum_kernel(const float* __restrict__ nb, const int* __restrict__ gid,
                              float* __restrict__ sn, int Nn) {
    size_t idx = (size_t)blockIdx.x * blockDim.x + threadIdx.x;
    if (idx >= (size_t)Nn * HD) return;
    size_t row = idx >> 7; int col = (int)(idx & 127);
    atomicAdd(&sn[(size_t)gid[row] * HD + col], nb[idx]);
}

__global__ void seg_scale_sum_kernel(const float* __restrict__ nb, const int* __restrict__ gid,
                                     const float* __restrict__ scale, float* __restrict__ out, int Nn) {
    size_t idx = (size_t)blockIdx.x * blockDim.x + threadIdx.x;
    if (idx >= (size_t)Nn * HD) return;
    size_t row = idx >> 7; int col = (int)(idx & 127);
    atomicAdd(&out[(size_t)gid[row] * HD + col], scale[row] * nb[idx]);
}

__global__ void final_kernel(const float* __restrict__ sn, const float* __restrict__ Wp,
                             const float* __restrict__ bp, float* __restrict__ out, int G) {
    int g = (blockIdx.x * blockDim.x + threadIdx.x) >> 6;
    int lane = threadIdx.x & 63;
    if (g >= G) return;
    const float* r = sn + (size_t)g * HD;
    float p = r[lane] * Wp[lane] + r[lane + 64] * Wp[lane + 64];
#pragma unroll
    for (int off = 32; off > 0; off >>= 1) p += __shfl_down(p, off);
    if (lane == 0) out[g] = p + bp[0];
}

__global__ void canary_kernel(float* out, int n) {
    int i = blockIdx.x * blockDim.x + threadIdx.x;
    if (i < n) out[i] = 123.456f;
}

struct PkB { const short* hi; const short* lo; int KG; };

extern "C" void kernel_launch(void* const* d_in, const int* in_sizes, int n_in,
                              void* d_out, int out_size, void* d_ws, size_t ws_size,
                              hipStream_t stream) {
    const float* node = (const float*)d_in[0];
    const float* edge = (const float*)d_in[1];
    const int*   src  = (const int*)d_in[2];
    const int*   dst  = (const int*)d_in[3];
    const int*   gid  = (const int*)d_in[4];
    const float* Wn0  = (const float*)d_in[5];
    const float* bn0  = (const float*)d_in[6];
    const float* We0  = (const float*)d_in[7];
    const float* be0  = (const float*)d_in[8];
    const float* aWn  = (const float*)d_in[9];
    const float* abn  = (const float*)d_in[10];
    const float* aWe  = (const float*)d_in[11];
    const float* abe  = (const float*)d_in[12];
    const float* aWal = (const float*)d_in[13];
    const float* abal = (const float*)d_in[14];
    const float* aWat = (const float*)d_in[15];
    const float* abat = (const float*)d_in[16];
    const float* aWih = (const float*)d_in[17];
    const float* abih = (const float*)d_in[18];
    const float* aWhh = (const float*)d_in[19];
    const float* abhh = (const float*)d_in[20];
    const float* mWal = (const float*)d_in[21];
    const float* mbal = (const float*)d_in[22];
    const float* mWat = (const float*)d_in[23];
    const float* mbat = (const float*)d_in[24];
    const float* mWih = (const float*)d_in[25];
    const float* mbih = (const float*)d_in[26];
    const float* mWhh = (const float*)d_in[27];
    const float* mbhh = (const float*)d_in[28];
    const float* Wp   = (const float*)d_in[29];
    const float* bp   = (const float*)d_in[30];

    const int N = in_sizes[0] / 64;
    const int E = in_sizes[1] / 16;
    const int G = out_size;
    const int D = in_sizes[9] / (HD * HD);
    const int L = in_sizes[21] / (2 * HD);
    if (D > 8 || L > 4) return;

    char* wsb = (char*)d_ws;

    // ---- weight pre-pack ----
    short* pkcur = (short*)wsb;
    auto packB = [&](const float* B, int K, int ldb, int col0, int Ncols) -> PkB {
        int KG = 4 * ((K + 31) / 32);
        size_t elems = (size_t)(Ncols >> 4) * KG * 16 * 8;
        short* hi = pkcur; pkcur += elems;
        short* lo = pkcur; pkcur += elems;
        int total = (Ncols >> 4) * KG * 16;
        pack_b_kernel<<<(total + 255) / 256, 256, 0, stream>>>(B, K, ldb, col0, Ncols, hi, lo);
        PkB p; p.hi = hi; p.lo = lo; p.KG = KG; return p;
    };
    PkB pWe0 = packB(We0, 16, HD, 0, HD);
    PkB pWn0 = packB(Wn0, 64, HD, 0, HD);
    PkB pAWn[8], pAWe[8], pAWat[8];
    const short *gHi[8], *gLo[8];
    for (int d = 0; d < D; ++d) {
        pAWn[d]  = packB(aWn  + (size_t)d * HD * HD,     HD,     HD, 0, HD);
        pAWe[d]  = packB(aWe  + (size_t)d * 2 * HD * HD, 2 * HD, HD, 0, HD);
        pAWat[d] = packB(aWat + (size_t)d * HD * HD,     HD,     HD, 0, HD);
        short* ghi = pkcur; pkcur += 6 * GRU_SL;
        short* glo = pkcur; pkcur += 6 * GRU_SL;
        for (int g = 0; g < 3; ++g) {
            int total = (HD >> 4) * 16 * 16;
            pack_b_kernel<<<(total + 255) / 256, 256, 0, stream>>>(
                aWih + (size_t)d * HD * H3, HD, H3, g * HD, HD, ghi + g * GRU_SL, glo + g * GRU_SL);
            pack_b_kernel<<<(total + 255) / 256, 256, 0, stream>>>(
                aWhh + (size_t)d * HD * H3, HD, H3, g * HD, HD, ghi + (3 + g) * GRU_SL, glo + (3 + g) * GRU_SL);
        }
        gHi[d] = ghi; gLo[d] = glo;
    }
    PkB pMWat[4], pMWih[4], pMWhh[4];
    for (int l = 0; l < L; ++l) {
        pMWat[l] = packB(mWat + (size_t)l * HD * HD, HD, HD, 0, HD);
        pMWih[l] = packB(mWih + (size_t)l * HD * H3, HD, H3, 0, H3);
        pMWhh[l] = packB(mWhh + (size_t)l * HD * H3, HD, H3, 0, H3);
    }

    // ---- fixed workspace ----
    size_t off = ((size_t)((char*)pkcur - wsb) + 255) & ~(size_t)255;
    auto alloc = [&](size_t bytes) -> void* {
        void* p = (void*)(wsb + off);
        off += (bytes + 255) & ~(size_t)255;
        return p;
    };
    float*    nbuf  = (float*)alloc((size_t)N * HD * 4);
    unsigned* hpk   = (unsigned*)alloc((size_t)N * HD * 4);
    float* sc_e = (float*)alloc((size_t)E * 4);
    float* nmax = (float*)alloc((size_t)N * 4);
    float* nsum = (float*)alloc((size_t)N * 4);
    float* sc_n = (float*)alloc((size_t)N * 4);
    float* hd2  = (float*)alloc((size_t)N * 4);
    float* sn   = (float*)alloc((size_t)G * HD * 4);
    float* gmax = (float*)alloc((size_t)G * 4);
    float* gsum = (float*)alloc((size_t)G * 4);
    int* cnt    = (int*)alloc((size_t)(N + 1) * 4);
    int* rowptr = (int*)alloc((size_t)(N + 1) * 4);
    int* fillc  = (int*)alloc((size_t)N * 4);
    int* csr    = (int*)alloc((size_t)E * 4);
    int* ipos   = (int*)alloc((size_t)E * 4);
    int* btot   = (int*)alloc(1024 * 4);

    // ---- overlay region OVR (msgpk | ctxpk | mol buffers) ----
    size_t ovr_off = off;
    size_t ctx_bytes = (size_t)N * HD * 4;
    size_t mol_bytes = 3 * ((size_t)G * HD * 4 + 256) + 2 * ((size_t)G * H3 * 4 + 256);
    size_t min_ovr = ctx_bytes > mol_bytes ? ctx_bytes : mol_bytes;
    int csr_mode, fullprec = 0;
    size_t mf = (size_t)E * HD * 4, mh = (size_t)E * HD * 2;
    if (ovr_off + (mf > min_ovr ? mf : min_ovr) <= ws_size) { csr_mode = 1; fullprec = 1; }
    else if (ovr_off + (mh > min_ovr ? mh : min_ovr) <= ws_size) { csr_mode = 1; fullprec = 0; }
    else if (ovr_off + min_ovr <= ws_size) { csr_mode = 0; }
    else {
        canary_kernel<<<(G + 255) / 256, 256, 0, stream>>>((float*)d_out, G);
        return;
    }
    void*     msgpk = (void*)(wsb + ovr_off);
    unsigned* ctxpk = (unsigned*)(wsb + ovr_off);
    // mol buffers carved inside OVR (used only after atom phase)
    size_t mo = ovr_off;
    auto molalloc = [&](size_t bytes) -> float* {
        float* p = (float*)(wsb + mo);
        mo += (bytes + 255) & ~(size_t)255;
        return p;
    };
    float* sbuf = molalloc((size_t)G * HD * 4);
    float* sctx = molalloc((size_t)G * HD * 4);
    float* Sg   = molalloc((size_t)G * HD * 4);
    float* gim  = molalloc((size_t)G * H3 * 4);
    float* ghm  = molalloc((size_t)G * H3 * 4);

    const int total_sc = N + 1;
    const int nb = (total_sc + 1023) / 1024;
    if (csr_mode && nb > 256) csr_mode = 0;

    auto mgemm = [&](const float* A, int K, const PkB& pk, const float* bias, void* C,
                     int M, int Nc, int act, const float* rdw, float* rdout,
                     const float* rowmask, int outpk) {
        dim3 g((M + 63) / 64, Nc / 64);
        mfma_gemm<<<g, dim3(256), 0, stream>>>(A, K, pk.hi, pk.lo, pk.KG, bias, (float*)C,
                                               M, Nc, act, rdw, rdout, rowmask, outpk);
    };

    // ---- CSR build (dst constant across depths) ----
    if (csr_mode) {
        hipMemsetAsync(cnt, 0, (size_t)(N + 1) * 4, stream);
        hipMemsetAsync(fillc, 0, (size_t)N * 4, stream);
        hist_kernel<<<(E + 255) / 256, 256, 0, stream>>>(dst, cnt, E);
        scan1_kernel<<<nb, 256, 0, stream>>>(cnt, rowptr, btot, total_sc);
        scan2_kernel<<<1, 256, 0, stream>>>(btot, nb);
        scan3_kernel<<<(total_sc + 255) / 256, 256, 0, stream>>>(rowptr, btot, total_sc);
        fill_kernel<<<(E + 255) / 256, 256, 0, stream>>>(dst, rowptr, fillc, csr, ipos, E);
    }

    // ---- input embedding ----
    mgemm(node, 64, pWn0, bn0, nbuf, N, HD, 1, nullptr, nullptr, nullptr, 0);

    // ---- atom-level message passing ----
    const int EB = (E + 63) / 64;
    for (int d = 0; d < D; ++d) {
        const float* bn_d  = abn  + (size_t)d * HD;
        const float* be_d  = abe  + (size_t)d * HD;
        const float* Wal_d = aWal + (size_t)d * 2 * HD;
        const float* bal_d = abal + d;
        const float* bat_d = abat + (size_t)d * HD;
        const float* bih_d = abih + (size_t)d * H3;
        const float* bhh_d = abhh + (size_t)d * H3;

        hipMemsetAsync(hd2, 0, (size_t)N * 4, stream);
        hipMemsetAsync(sc_e, 0, (size_t)E * 4, stream);
        // h = lrelu(n @ Wn + bn) -> packed; rowdot hd2 = h . Wal[128:256]
        mgemm(nbuf, HD, pAWn[d], bn_d, hpk, N, HD, 1, Wal_d + HD, hd2, nullptr, 1);
        init_maxsum_kernel<<<(N + 255) / 256, 256, 0, stream>>>(nmax, nsum, N);
        // pass A: score rowdot (+ CSR msg store in csr_mode)
        msg_pass_kernel<<<EB, 256, 0, stream>>>(hpk, src, dst, edge, pWe0.hi, pWe0.lo, be0,
                                                pAWe[d].hi, pAWe[d].lo, be_d, Wal_d,
                                                sc_e, nullptr, ipos, msgpk, fullprec, E,
                                                csr_mode ? 0 : 1);
        score_combine_kernel<<<(E + 255) / 256, 256, 0, stream>>>(sc_e, hd2, dst, bal_d, nmax, E);
        expsum_kernel<<<(E + 255) / 256, 256, 0, stream>>>(sc_e, nmax, nsum, dst, E);
        attdiv_kernel<<<(E + 255) / 256, 256, 0, stream>>>(sc_e, nsum, dst, E);
        if (csr_mode) {
            // S (nbuf) = segsum(att * msg), contiguous per node
            ctx_gather_kernel<<<(N + 3) / 4, 256, 0, stream>>>(msgpk, sc_e, csr, rowptr,
                                                               nbuf, N, fullprec);
        } else {
            // fallback: recompute msg, atomic scatter
            hipMemsetAsync(nbuf, 0, (size_t)N * HD * 4, stream);
            msg_pass_kernel<<<EB, 256, 0, stream>>>(hpk, src, dst, edge, pWe0.hi, pWe0.lo, be0,
                                                    pAWe[d].hi, pAWe[d].lo, be_d, nullptr,
                                                    sc_e, nbuf, nullptr, nullptr, 0, E, 2);
        }
        // ctx = elu(S @ Wat + bat) -> packed (OVR, msgpk dead); empty rows -> 0
        mgemm(nbuf, HD, pAWat[d], bat_d, ctxpk, N, HD, 3, nullptr, nullptr, nsum, 1);
        // n = relu(GRU(ctx, h)) -> nbuf
        dim3 gg((N + 63) / 64, 2);
        gru_fused_kernel<<<gg, dim3(256), 0, stream>>>(ctxpk, hpk, gHi[d], gLo[d],
                                                       bih_d, bhh_d, nbuf, N);
    }

    // ---- molecule-level readout (mol buffers live in OVR; ctxpk dead) ----
    hipMemsetAsync(sn, 0, (size_t)G * HD * 4, stream);
    segsum_kernel<<<((size_t)N * HD + 255) / 256, 256, 0, stream>>>(nbuf, gid, sn, N);
    for (int l = 0; l < L; ++l) {
        const float* Wal_l = mWal + (size_t)l * 2 * HD;
        const float* bal_l = mbal + l;
        const float* bat_l = mbat + (size_t)l * HD;
        const float* bih_l = mbih + (size_t)l * H3;
        const float* bhh_l = mbhh + (size_t)l * H3;

        lrelu_copy_kernel<<<((size_t)G * HD + 255) / 256, 256, 0, stream>>>(sn, sbuf, (size_t)G * HD);
        init_maxsum_kernel<<<(G + 255) / 256, 256, 0, stream>>>(gmax, gsum, G);
        score_kernel<<<(N + 3) / 4, 256, 0, stream>>>(nbuf, sbuf, gid, Wal_l, bal_l, sc_n, gmax, N);
        expsum_kernel<<<(N + 255) / 256, 256, 0, stream>>>(sc_n, gmax, gsum, gid, N);
        attdiv_kernel<<<(N + 255) / 256, 256, 0, stream>>>(sc_n, gsum, gid, N);
        hipMemsetAsync(Sg, 0, (size_t)G * HD * 4, stream);
        seg_scale_sum_kernel<<<((size_t)N * HD + 255) / 256, 256, 0, stream>>>(nbuf, gid, sc_n, Sg, N);
        mgemm(Sg, HD, pMWat[l], bat_l, sctx, G, HD, 3, nullptr, nullptr, gsum, 0);
        mgemm(sctx, HD, pMWih[l], bih_l, gim, G, H3, 0, nullptr, nullptr, nullptr, 0);
        mgemm(sbuf, HD, pMWhh[l], bhh_l, ghm, G, H3, 0, nullptr, nullptr, nullptr, 0);
        gru_gate_kernel<<<((size_t)G * HD + 255) / 256, 256, 0, stream>>>(gim, ghm, sbuf, sn, G);
    }

    // ---- final prediction ----
    final_kernel<<<(G + 3) / 4, 256, 0, stream>>>(sn, Wp, bp, (float*)d_out, G);
}

// Round 13
// 1845.446 us; speedup vs baseline: 1.3718x; 1.1422x over previous
//
#include <hip/hip_runtime.h>
#include <hip/hip_bf16.h>
#include <math.h>

// AttentiveFP forward. Split-bf16 (3-term) MFMA engine.
//  - CSR-by-dst, POSITION-ORDERED edges (srcp/dstp/eidp): msg stores and
//    score atomics sequential; ctx = contiguous gather (no atomics).
//  - node state & gathered S stored packed u32 (bf16 hi|lo): GEMM A-loads
//    are cheap unpacks (apk), not f32 splits.
//  - tiered msg storage (u32 / bf16 / atomic-scatter fallback), OVR overlay.
//  - batched weight packing (9 launches).
// H=128, 3H=384.

#define HD 128
#define H3 384

typedef __attribute__((ext_vector_type(8))) short short8;
typedef __attribute__((ext_vector_type(4))) float f32x4;

__device__ __forceinline__ float lrelu_f(float x) { return x > 0.f ? x : 0.01f * x; }
__device__ __forceinline__ float sigmoid_f(float x) { return 1.f / (1.f + expf(-x)); }

__device__ __forceinline__ void atomicMaxF(float* addr, float val) {
    int iv = __float_as_int(val);
    if (iv >= 0) atomicMax((int*)addr, iv);
    else atomicMin((unsigned int*)addr, (unsigned int)iv);
}

__device__ __forceinline__ unsigned short bf16_rne(float v, float* back) {
    unsigned u = __float_as_uint(v);
    unsigned r = (u + 0x7FFFu + ((u >> 16) & 1u)) >> 16;
    *back = __uint_as_float(r << 16);
    return (unsigned short)r;
}

__device__ __forceinline__ unsigned pack_hl(float v) {
    float back, d;
    unsigned short h = bf16_rne(v, &back);
    unsigned short l = bf16_rne(v - back, &d);
    return ((unsigned)h << 16) | (unsigned)l;
}
__device__ __forceinline__ float unpack_f32(unsigned w) {
    return __uint_as_float(w & 0xffff0000u) + __uint_as_float(w << 16);
}

__device__ __forceinline__ void split8(const float* p, short8& h8, short8& l8) {
    float4 u0 = *reinterpret_cast<const float4*>(p);
    float4 u1 = *reinterpret_cast<const float4*>(p + 4);
    float vv[8] = {u0.x, u0.y, u0.z, u0.w, u1.x, u1.y, u1.z, u1.w};
#pragma unroll
    for (int j = 0; j < 8; ++j) {
        float back, d;
        h8[j] = (short)bf16_rne(vv[j], &back);
        l8[j] = (short)bf16_rne(vv[j] - back, &d);
    }
}

__device__ __forceinline__ void unpack8(const unsigned* p, short8& h8, short8& l8) {
    uint4 w0 = *reinterpret_cast<const uint4*>(p);
    uint4 w1 = *reinterpret_cast<const uint4*>(p + 4);
    unsigned ww[8] = {w0.x, w0.y, w0.z, w0.w, w1.x, w1.y, w1.z, w1.w};
#pragma unroll
    for (int j = 0; j < 8; ++j) {
        h8[j] = (short)(ww[j] >> 16);
        l8[j] = (short)(ww[j] & 0xffffu);
    }
}

// ---------------------------------------------------------------------------
// Batched pack: blockIdx.y = matrix index (B += mat*matB, out += mat*matO).
// Layout per matrix: [nblk][kg][col16][e8], KG = 4*ceil(K/32).
// ---------------------------------------------------------------------------
__global__ void pack_b_kernel(const float* __restrict__ B, int K, int ldb, int col0,
                              int Ncols, short* __restrict__ hi, short* __restrict__ lo,
                              size_t matB, size_t matO) {
    int KG = 4 * ((K + 31) / 32);
    int mat = blockIdx.y;
    B += (size_t)mat * matB;
    hi += (size_t)mat * matO;
    lo += (size_t)mat * matO;
    int idx = blockIdx.x * blockDim.x + threadIdx.x;
    int total = (Ncols >> 4) * KG * 16;
    if (idx >= total) return;
    int col = idx & 15;
    int kg = (idx >> 4) % KG;
    int nblk = idx / (16 * KG);
    size_t o = (size_t)idx * 8;
#pragma unroll
    for (int e = 0; e < 8; ++e) {
        int k = kg * 8 + e;
        float v = (k < K) ? B[(size_t)k * ldb + col0 + nblk * 16 + col] : 0.f;
        float hf, d;
        unsigned short h = bf16_rne(v, &hf);
        unsigned short l = bf16_rne(v - hf, &d);
        hi[o + e] = (short)h;
        lo[o + e] = (short)l;
    }
}

// GRU gate pack: all depths, 6 slices (ih r,z,n ; hh r,z,n), one launch.
#define GRU_SL (8 * 16 * 16 * 8)
__global__ void pack_gru_kernel(const float* __restrict__ Wih, const float* __restrict__ Whh,
                                int D, short* __restrict__ hi, short* __restrict__ lo) {
    const int per = 6 * (GRU_SL / 8);
    int idx = blockIdx.x * blockDim.x + threadIdx.x;
    if (idx >= D * per) return;
    int d = idx / per;
    int r = idx % per;
    int s = r / (GRU_SL / 8);
    int g8 = r % (GRU_SL / 8);
    int col = g8 & 15;
    int kg = (g8 >> 4) & 15;
    int nblk = g8 >> 8;
    const float* B = (s < 3 ? Wih : Whh) + (size_t)d * HD * H3;
    int col0 = (s % 3) * HD;
    size_t o = (size_t)idx * 8;
#pragma unroll
    for (int e = 0; e < 8; ++e) {
        int k = kg * 8 + e;
        float v = B[(size_t)k * H3 + col0 + nblk * 16 + col];
        float hf, d2;
        unsigned short h = bf16_rne(v, &hf);
        unsigned short l = bf16_rne(v - hf, &d2);
        hi[o + e] = (short)h;
        lo[o + e] = (short)l;
    }
}

// ---------------------------------------------------------------------------
// Generic split-bf16 GEMM. apk: A is packed u32 hi|lo (unpack instead of split).
// outpk: C stored packed. rowdot/rowmask as before.
// ---------------------------------------------------------------------------
__global__ __launch_bounds__(256) void mfma_gemm(
    const float* __restrict__ A, int K,
    const short* __restrict__ Bhi, const short* __restrict__ Blo, int KG,
    const float* __restrict__ bias, float* __restrict__ C, int M, int N, int act,
    const float* __restrict__ rdw, float* __restrict__ rdout,
    const float* __restrict__ rowmask, int outpk, int apk)
{
    const int t = threadIdx.x, lane = t & 63, w = t >> 6;
    const int wm = w & 1, wn = w >> 1, q = lane >> 4, r16 = lane & 15;
    const int m0 = blockIdx.x * 64, n0 = blockIdx.y * 64;
    const int KT = K >> 5;

    f32x4 acc[2][2];
#pragma unroll
    for (int a = 0; a < 2; ++a)
#pragma unroll
        for (int b = 0; b < 2; ++b) { acc[a][b][0]=0.f; acc[a][b][1]=0.f; acc[a][b][2]=0.f; acc[a][b][3]=0.f; }

    int arow[2];
#pragma unroll
    for (int mt = 0; mt < 2; ++mt) {
        int m = m0 + (wm << 5) + (mt << 4) + r16;
        arow[mt] = (m >= M) ? M - 1 : m;
    }

    for (int kt = 0; kt < KT; ++kt) {
        short8 ah[2], al[2];
#pragma unroll
        for (int mt = 0; mt < 2; ++mt) {
            size_t aoff = (size_t)arow[mt] * K + (kt << 5) + (q << 3);
            if (apk) unpack8((const unsigned*)A + aoff, ah[mt], al[mt]);
            else split8(A + aoff, ah[mt], al[mt]);
        }
        const int kg = (kt << 2) + q;
#pragma unroll
        for (int nt = 0; nt < 2; ++nt) {
            int nblk = (n0 >> 4) + (wn << 1) + nt;
            size_t boff = (((size_t)nblk * KG + kg) * 16 + r16) * 8;
            short8 bh = *reinterpret_cast<const short8*>(Bhi + boff);
            short8 bl = *reinterpret_cast<const short8*>(Blo + boff);
#pragma unroll
            for (int mt = 0; mt < 2; ++mt) {
                acc[mt][nt] = __builtin_amdgcn_mfma_f32_16x16x32_bf16(ah[mt], bh, acc[mt][nt], 0, 0, 0);
                acc[mt][nt] = __builtin_amdgcn_mfma_f32_16x16x32_bf16(ah[mt], bl, acc[mt][nt], 0, 0, 0);
                acc[mt][nt] = __builtin_amdgcn_mfma_f32_16x16x32_bf16(al[mt], bh, acc[mt][nt], 0, 0, 0);
            }
        }
    }

#pragma unroll
    for (int mt = 0; mt < 2; ++mt) {
        float pv[4] = {0.f, 0.f, 0.f, 0.f};
#pragma unroll
        for (int nt = 0; nt < 2; ++nt) {
            int col = n0 + (wn << 5) + (nt << 4) + r16;
            float bi = bias ? bias[col] : 0.f;
            float wc = rdw ? rdw[col] : 0.f;
#pragma unroll
            for (int i = 0; i < 4; ++i) {
                int m = m0 + (wm << 5) + (mt << 4) + (q << 2) + i;
                float v = acc[mt][nt][i] + bi;
                if (act == 1) v = v > 0.f ? v : 0.01f * v;
                else if (act == 2) v = fmaxf(v, 0.f);
                else if (act == 3) v = v > 0.f ? v : expf(v) - 1.f;
                if (rowmask && m < M && rowmask[m] == 0.f) v = 0.f;
                pv[i] += wc * v;
                if (m < M) {
                    if (outpk) ((unsigned*)C)[(size_t)m * N + col] = pack_hl(v);
                    else C[(size_t)m * N + col] = v;
                }
            }
        }
        if (rdw) {
#pragma unroll
            for (int i = 0; i < 4; ++i) {
                float p = pv[i];
                p += __shfl_xor(p, 1); p += __shfl_xor(p, 2);
                p += __shfl_xor(p, 4); p += __shfl_xor(p, 8);
                int m = m0 + (wm << 5) + (mt << 4) + (q << 2) + i;
                if (r16 == 0 && m < M) atomicAdd(&rdout[m], p);
            }
        }
    }
}

// ---------------------------------------------------------------------------
// Fused edge kernel, POSITION-ordered (m = CSR position). e computed on the
// fly (LDS) from edge[eidp[m]]; h gathered via srcp[m] (the only random access).
// mode 0: rowdot sc[m] + store msg row m (sequential)
// mode 1: rowdot only   mode 2: scatter S[dstp[m]] += sc[m]*msg (fallback)
// ---------------------------------------------------------------------------
__global__ __launch_bounds__(256) void msg_pass_kernel(
    const unsigned* __restrict__ hpk, const int* __restrict__ srcp,
    const int* __restrict__ dstp, const int* __restrict__ eidp,
    const float* __restrict__ edge,
    const short* __restrict__ W0hi, const short* __restrict__ W0lo,
    const float* __restrict__ be0,
    const short* __restrict__ Wehi, const short* __restrict__ Welo,
    const float* __restrict__ be,
    const float* __restrict__ wal,
    float* __restrict__ sc, float* __restrict__ S,
    void* __restrict__ msgpk, int fullprec,
    int E, int mode)
{
    __shared__ unsigned int elds[64 * 128];
    const int t = threadIdx.x, lane = t & 63, w = t >> 6;
    const int wm = w & 1, wn = w >> 1, q = lane >> 4, r16 = lane & 15;
    const int e0 = blockIdx.x * 64;

    // ---- stage 1: e tile ----
    {
        f32x4 ea[2][4];
#pragma unroll
        for (int a = 0; a < 2; ++a)
#pragma unroll
            for (int b = 0; b < 4; ++b) { ea[a][b][0]=0.f; ea[a][b][1]=0.f; ea[a][b][2]=0.f; ea[a][b][3]=0.f; }
        short8 eah[2], eal[2];
#pragma unroll
        for (int mt = 0; mt < 2; ++mt) {
            int er = e0 + (wm << 5) + (mt << 4) + r16;
            if (er >= E) er = E - 1;
            int eid = eidp[er];
            if (q < 2) split8(edge + (size_t)eid * 16 + (q << 3), eah[mt], eal[mt]);
            else {
#pragma unroll
                for (int j = 0; j < 8; ++j) { eah[mt][j] = 0; eal[mt][j] = 0; }
            }
        }
#pragma unroll
        for (int nt = 0; nt < 4; ++nt) {
            int nblk = (wn << 2) + nt;
            size_t boff = (((size_t)nblk * 4 + q) * 16 + r16) * 8;
            short8 bh = *reinterpret_cast<const short8*>(W0hi + boff);
            short8 bl = *reinterpret_cast<const short8*>(W0lo + boff);
#pragma unroll
            for (int mt = 0; mt < 2; ++mt) {
                ea[mt][nt] = __builtin_amdgcn_mfma_f32_16x16x32_bf16(eah[mt], bh, ea[mt][nt], 0, 0, 0);
                ea[mt][nt] = __builtin_amdgcn_mfma_f32_16x16x32_bf16(eah[mt], bl, ea[mt][nt], 0, 0, 0);
                ea[mt][nt] = __builtin_amdgcn_mfma_f32_16x16x32_bf16(eal[mt], bh, ea[mt][nt], 0, 0, 0);
            }
        }
#pragma unroll
        for (int mt = 0; mt < 2; ++mt)
#pragma unroll
            for (int nt = 0; nt < 4; ++nt) {
                int col = (wn << 6) + (nt << 4) + r16;
#pragma unroll
                for (int i = 0; i < 4; ++i) {
                    int row = (wm << 5) + (mt << 4) + (q << 2) + i;
                    float v = lrelu_f(ea[mt][nt][i] + be0[col]);
                    elds[row * 128 + (col ^ ((row & 7) << 2))] = pack_hl(v);
                }
            }
    }
    __syncthreads();

    // ---- stage 2: msg ----
    f32x4 acc[2][4];
#pragma unroll
    for (int a = 0; a < 2; ++a)
#pragma unroll
        for (int b = 0; b < 4; ++b) { acc[a][b][0]=0.f; acc[a][b][1]=0.f; acc[a][b][2]=0.f; acc[a][b][3]=0.f; }
    int grow[2], arw[2];
#pragma unroll
    for (int mt = 0; mt < 2; ++mt) {
        int m = e0 + (wm << 5) + (mt << 4) + r16;
        if (m >= E) m = E - 1;
        grow[mt] = srcp[m];
        arw[mt] = (wm << 5) + (mt << 4) + r16;
    }
#pragma unroll
    for (int kt = 0; kt < 8; ++kt) {
        short8 ah[2], al[2];
#pragma unroll
        for (int mt = 0; mt < 2; ++mt) {
            if (kt < 4) {
                unpack8(hpk + (size_t)grow[mt] * HD + (kt << 5) + (q << 3), ah[mt], al[mt]);
            } else {
                int row = arw[mt];
                int sh = (row & 7) << 2;
                int c = ((kt - 4) << 5) + (q << 3);
                uint4 w0 = *reinterpret_cast<const uint4*>(&elds[row * 128 + (c ^ sh)]);
                uint4 w1 = *reinterpret_cast<const uint4*>(&elds[row * 128 + ((c + 4) ^ sh)]);
                unsigned ww[8] = {w0.x, w0.y, w0.z, w0.w, w1.x, w1.y, w1.z, w1.w};
#pragma unroll
                for (int j = 0; j < 8; ++j) {
                    ah[mt][j] = (short)(ww[j] >> 16);
                    al[mt][j] = (short)(ww[j] & 0xffffu);
                }
            }
        }
        const int kg = (kt << 2) + q;
#pragma unroll
        for (int nt = 0; nt < 4; ++nt) {
            int nblk = (wn << 2) + nt;
            size_t boff = (((size_t)nblk * 32 + kg) * 16 + r16) * 8;
            short8 bh = *reinterpret_cast<const short8*>(Wehi + boff);
            short8 bl = *reinterpret_cast<const short8*>(Welo + boff);
#pragma unroll
            for (int mt = 0; mt < 2; ++mt) {
                acc[mt][nt] = __builtin_amdgcn_mfma_f32_16x16x32_bf16(ah[mt], bh, acc[mt][nt], 0, 0, 0);
                acc[mt][nt] = __builtin_amdgcn_mfma_f32_16x16x32_bf16(ah[mt], bl, acc[mt][nt], 0, 0, 0);
                acc[mt][nt] = __builtin_amdgcn_mfma_f32_16x16x32_bf16(al[mt], bh, acc[mt][nt], 0, 0, 0);
            }
        }
    }

    if (mode == 2) {
#pragma unroll
        for (int mt = 0; mt < 2; ++mt)
#pragma unroll
            for (int i = 0; i < 4; ++i) {
                int m = e0 + (wm << 5) + (mt << 4) + (q << 2) + i;
                if (m >= E) continue;
                float a = sc[m];
                int dn = dstp[m];
#pragma unroll
                for (int nt = 0; nt < 4; ++nt) {
                    int col = (wn << 6) + (nt << 4) + r16;
                    float v = lrelu_f(acc[mt][nt][i] + be[col]);
                    atomicAdd(&S[(size_t)dn * HD + col], a * v);
                }
            }
        return;
    }

    // mode 0/1: rowdot score (+ sequential msg store in mode 0)
#pragma unroll
    for (int mt = 0; mt < 2; ++mt) {
        float pv[4] = {0.f, 0.f, 0.f, 0.f};
#pragma unroll
        for (int i = 0; i < 4; ++i) {
            int m = e0 + (wm << 5) + (mt << 4) + (q << 2) + i;
#pragma unroll
            for (int nt = 0; nt < 4; ++nt) {
                int col = (wn << 6) + (nt << 4) + r16;
                float v = lrelu_f(acc[mt][nt][i] + be[col]);
                pv[i] += wal[col] * v;
                if (mode == 0 && m < E) {
                    size_t ro = (size_t)m * HD + col;
                    if (fullprec) ((unsigned*)msgpk)[ro] = pack_hl(v);
                    else { float b_; ((unsigned short*)msgpk)[ro] = bf16_rne(v, &b_); }
                }
            }
        }
#pragma unroll
        for (int i = 0; i < 4; ++i) {
            float p = pv[i];
            p += __shfl_xor(p, 1); p += __shfl_xor(p, 2);
            p += __shfl_xor(p, 4); p += __shfl_xor(p, 8);
            int m = e0 + (wm << 5) + (mt << 4) + (q << 2) + i;
            if (r16 == 0 && m < E) atomicAdd(&sc[m], p);
        }
    }
}

// ---------------------------------------------------------------------------
// ctx gather: one wave per node; msg rows & sc contiguous. Writes PACKED S.
// ---------------------------------------------------------------------------
__global__ __launch_bounds__(256) void ctx_gather_kernel(
    const void* __restrict__ msgpk, const float* __restrict__ sc,
    const int* __restrict__ rowptr, unsigned* __restrict__ Spk, int Nn, int fullprec)
{
    int wid = (blockIdx.x * blockDim.x + threadIdx.x) >> 6;
    int lane = threadIdx.x & 63;
    if (wid >= Nn) return;
    int p0 = rowptr[wid], p1 = rowptr[wid + 1];
    float a0 = 0.f, a1 = 0.f;
    if (fullprec) {
        const unsigned* mp = (const unsigned*)msgpk;
        for (int p = p0; p < p1; ++p) {
            float a = sc[p];
            uint2 w = *reinterpret_cast<const uint2*>(mp + (size_t)p * HD + lane * 2);
            a0 += a * unpack_f32(w.x);
            a1 += a * unpack_f32(w.y);
        }
    } else {
        const unsigned short* mp = (const unsigned short*)msgpk;
        for (int p = p0; p < p1; ++p) {
            float a = sc[p];
            unsigned w = *reinterpret_cast<const unsigned*>(mp + (size_t)p * HD + lane * 2);
            a0 += a * __uint_as_float(w << 16);
            a1 += a * __uint_as_float(w & 0xffff0000u);
        }
    }
    Spk[(size_t)wid * HD + lane * 2] = pack_hl(a0);
    Spk[(size_t)wid * HD + lane * 2 + 1] = pack_hl(a1);
}

// ---- CSR build ----
__global__ void hist_kernel(const int* __restrict__ dst, int* __restrict__ cnt, int E) {
    int i = blockIdx.x * blockDim.x + threadIdx.x;
    if (i < E) atomicAdd(&cnt[dst[i]], 1);
}
__global__ void scan1_kernel(const int* __restrict__ cnt, int* __restrict__ pre,
                             int* __restrict__ btot, int total) {
    __shared__ int ts[256];
    int base = blockIdx.x * 1024;
    int c[4], tsum = 0;
#pragma unroll
    for (int j = 0; j < 4; ++j) {
        int idx = base + threadIdx.x * 4 + j;
        c[j] = (idx < total) ? cnt[idx] : 0;
        tsum += c[j];
    }
    ts[threadIdx.x] = tsum;
    __syncthreads();
    for (int off = 1; off < 256; off <<= 1) {
        int v = (threadIdx.x >= off) ? ts[threadIdx.x - off] : 0;
        __syncthreads();
        ts[threadIdx.x] += v;
        __syncthreads();
    }
    int run = ts[threadIdx.x] - tsum;
#pragma unroll
    for (int j = 0; j < 4; ++j) {
        int idx = base + threadIdx.x * 4 + j;
        if (idx < total) pre[idx] = run;
        run += c[j];
    }
    if (threadIdx.x == 255) btot[blockIdx.x] = ts[255];
}
__global__ void scan2_kernel(int* __restrict__ btot, int nb) {
    __shared__ int ts[256];
    int v = (threadIdx.x < nb) ? btot[threadIdx.x] : 0;
    ts[threadIdx.x] = v;
    __syncthreads();
    for (int off = 1; off < 256; off <<= 1) {
        int u = (threadIdx.x >= off) ? ts[threadIdx.x - off] : 0;
        __syncthreads();
        ts[threadIdx.x] += u;
        __syncthreads();
    }
    if (threadIdx.x < nb) btot[threadIdx.x] = ts[threadIdx.x] - v;
}
__global__ void scan3_kernel(int* __restrict__ pre, const int* __restrict__ btot, int total) {
    int i = blockIdx.x * blockDim.x + threadIdx.x;
    if (i < total) pre[i] += btot[i >> 10];
}
// fill: writes position-ordered src/dst/eid arrays directly
__global__ void fill_kernel(const int* __restrict__ src, const int* __restrict__ dst,
                            const int* __restrict__ rowptr, int* __restrict__ fillc,
                            int* __restrict__ srcp, int* __restrict__ dstp,
                            int* __restrict__ eidp, int E) {
    int i = blockIdx.x * blockDim.x + threadIdx.x;
    if (i >= E) return;
    int d = dst[i];
    int pos = rowptr[d] + atomicAdd(&fillc[d], 1);
    srcp[pos] = src[i];
    dstp[pos] = d;
    eidp[pos] = i;
}

// ---------------------------------------------------------------------------
// Fused GRU: out = relu(GRU(ctx, h)) -> PACKED npk. ctx/h read packed.
// ---------------------------------------------------------------------------
__global__ __launch_bounds__(256) void gru_fused_kernel(
    const unsigned* __restrict__ ctxpk, const unsigned* __restrict__ hpk,
    const short* __restrict__ ghi, const short* __restrict__ glo,
    const float* __restrict__ bih, const float* __restrict__ bhh,
    unsigned* __restrict__ out, int M)
{
    const int t = threadIdx.x, lane = t & 63, w = t >> 6;
    const int wm = w & 1, wn = w >> 1, q = lane >> 4, r16 = lane & 15;
    const int m0 = blockIdx.x * 64, j0 = blockIdx.y * 64;

    f32x4 acc[6][2][2];
#pragma unroll
    for (int g = 0; g < 6; ++g)
#pragma unroll
        for (int a = 0; a < 2; ++a)
#pragma unroll
            for (int b = 0; b < 2; ++b) { acc[g][a][b][0]=0.f; acc[g][a][b][1]=0.f; acc[g][a][b][2]=0.f; acc[g][a][b][3]=0.f; }

    int arow[2];
#pragma unroll
    for (int mt = 0; mt < 2; ++mt) {
        int m = m0 + (wm << 5) + (mt << 4) + r16;
        arow[mt] = (m >= M) ? M - 1 : m;
    }

#pragma unroll
    for (int kt = 0; kt < 4; ++kt) {
        short8 ah[2], al[2];
#pragma unroll
        for (int mt = 0; mt < 2; ++mt)
            unpack8(ctxpk + (size_t)arow[mt] * HD + (kt << 5) + (q << 3), ah[mt], al[mt]);
        const int kg = (kt << 2) + q;
#pragma unroll
        for (int g = 0; g < 3; ++g)
#pragma unroll
            for (int nt = 0; nt < 2; ++nt) {
                int nblk = (j0 >> 4) + (wn << 1) + nt;
                size_t boff = (size_t)g * GRU_SL + (((size_t)nblk * 16 + kg) * 16 + r16) * 8;
                short8 bh = *reinterpret_cast<const short8*>(ghi + boff);
                short8 bl = *reinterpret_cast<const short8*>(glo + boff);
#pragma unroll
                for (int mt = 0; mt < 2; ++mt) {
                    acc[g][mt][nt] = __builtin_amdgcn_mfma_f32_16x16x32_bf16(ah[mt], bh, acc[g][mt][nt], 0, 0, 0);
                    acc[g][mt][nt] = __builtin_amdgcn_mfma_f32_16x16x32_bf16(ah[mt], bl, acc[g][mt][nt], 0, 0, 0);
                    acc[g][mt][nt] = __builtin_amdgcn_mfma_f32_16x16x32_bf16(al[mt], bh, acc[g][mt][nt], 0, 0, 0);
                }
            }
    }
#pragma unroll
    for (int kt = 0; kt < 4; ++kt) {
        short8 ah[2], al[2];
#pragma unroll
        for (int mt = 0; mt < 2; ++mt)
            unpack8(hpk + (size_t)arow[mt] * HD + (kt << 5) + (q << 3), ah[mt], al[mt]);
        const int kg = (kt << 2) + q;
#pragma unroll
        for (int g = 3; g < 6; ++g)
#pragma unroll
            for (int nt = 0; nt < 2; ++nt) {
                int nblk = (j0 >> 4) + (wn << 1) + nt;
                size_t boff = (size_t)g * GRU_SL + (((size_t)nblk * 16 + kg) * 16 + r16) * 8;
                short8 bh = *reinterpret_cast<const short8*>(ghi + boff);
                short8 bl = *reinterpret_cast<const short8*>(glo + boff);
#pragma unroll
                for (int mt = 0; mt < 2; ++mt) {
                    acc[g][mt][nt] = __builtin_amdgcn_mfma_f32_16x16x32_bf16(ah[mt], bh, acc[g][mt][nt], 0, 0, 0);
                    acc[g][mt][nt] = __builtin_amdgcn_mfma_f32_16x16x32_bf16(ah[mt], bl, acc[g][mt][nt], 0, 0, 0);
                    acc[g][mt][nt] = __builtin_amdgcn_mfma_f32_16x16x32_bf16(al[mt], bh, acc[g][mt][nt], 0, 0, 0);
                }
            }
    }

#pragma unroll
    for (int mt = 0; mt < 2; ++mt)
#pragma unroll
        for (int nt = 0; nt < 2; ++nt) {
            int j = j0 + (wn << 5) + (nt << 4) + r16;
            float bir = bih[j], biz = bih[HD + j], bin = bih[2 * HD + j];
            float bhr = bhh[j], bhz = bhh[HD + j], bhn = bhh[2 * HD + j];
#pragma unroll
            for (int i = 0; i < 4; ++i) {
                int m = m0 + (wm << 5) + (mt << 4) + (q << 2) + i;
                if (m >= M) continue;
                float r = sigmoid_f(acc[0][mt][nt][i] + bir + acc[3][mt][nt][i] + bhr);
                float z = sigmoid_f(acc[1][mt][nt][i] + biz + acc[4][mt][nt][i] + bhz);
                float hn = acc[5][mt][nt][i] + bhn;
                float nn = tanhf(acc[2][mt][nt][i] + bin + r * hn);
                float hv = unpack_f32(hpk[(size_t)m * HD + j]);
                out[(size_t)m * HD + j] = pack_hl(fmaxf((1.f - z) * nn + z * hv, 0.f));
            }
        }
}

__global__ void init_maxsum_kernel(float* mx, float* sm, int n) {
    int i = blockIdx.x * blockDim.x + threadIdx.x;
    if (i < n) { mx[i] = -__builtin_inff(); sm[i] = 0.f; }
}

__global__ void score_combine_kernel(float* __restrict__ sc, const float* __restrict__ hd2,
                                     const int* __restrict__ seg, const float* __restrict__ bal,
                                     float* __restrict__ maxbuf, int count) {
    int i = blockIdx.x * blockDim.x + threadIdx.x;
    if (i >= count) return;
    int s = seg[i];
    float v = lrelu_f(sc[i] + hd2[s] + bal[0]);
    sc[i] = v;
    atomicMaxF(&maxbuf[s], v);
}

// mol-phase score: A rows packed (node state), B rows f32 (mol state)
__global__ __launch_bounds__(256) void score_kernel(
    const unsigned* __restrict__ Apk, const float* __restrict__ B,
    const int* __restrict__ seg, const float* __restrict__ w,
    const float* __restrict__ bal, float* __restrict__ out,
    float* __restrict__ maxbuf, int count)
{
    int i = (blockIdx.x * blockDim.x + threadIdx.x) >> 6;
    int lane = threadIdx.x & 63;
    if (i >= count) return;
    int s = seg[i];
    float a0 = unpack_f32(Apk[(size_t)i * HD + lane]);
    float a1 = unpack_f32(Apk[(size_t)i * HD + lane + 64]);
    const float* br = B + (size_t)s * HD;
    float p = a0 * w[lane] + a1 * w[lane + 64]
            + br[lane] * w[128 + lane] + br[lane + 64] * w[192 + lane];
#pragma unroll
    for (int off = 32; off > 0; off >>= 1) p += __shfl_down(p, off);
    if (lane == 0) {
        float v = lrelu_f(p + bal[0]);
        out[i] = v;
        atomicMaxF(&maxbuf[s], v);
    }
}

__global__ void expsum_kernel(float* __restrict__ sc, const float* __restrict__ mx,
                              float* __restrict__ sm, const int* __restrict__ seg, int count) {
    int i = blockIdx.x * blockDim.x + threadIdx.x;
    if (i >= count) return;
    int s = seg[i];
    float p = expf(sc[i] - mx[s]);
    sc[i] = p;
    atomicAdd(&sm[s], p);
}

__global__ void attdiv_kernel(float* __restrict__ sc, const float* __restrict__ sm,
                              const int* __restrict__ seg, int count) {
    int i = blockIdx.x * blockDim.x + threadIdx.x;
    if (i >= count) return;
    sc[i] = sc[i] / sm[seg[i]];
}

__global__ void gru_gate_kernel(const float* __restrict__ gi, const float* __restrict__ gh,
                                const float* __restrict__ h, float* __restrict__ out, int M) {
    size_t idx = (size_t)blockIdx.x * blockDim.x + threadIdx.x;
    if (idx >= (size_t)M * HD) return;
    size_t row = idx >> 7; int col = (int)(idx & 127);
    const float* gir = gi + row * H3;
    const float* ghr = gh + row * H3;
    float r = sigmoid_f(gir[col] + ghr[col]);
    float z = sigmoid_f(gir[col + 128] + ghr[col + 128]);
    float nn = tanhf(gir[col + 256] + r * ghr[col + 256]);
    float o = (1.f - z) * nn + z * h[idx];
    out[idx] = fmaxf(o, 0.f);
}

__global__ void lrelu_copy_kernel(const float* __restrict__ in, float* __restrict__ out, size_t n) {
    size_t i = (size_t)blockIdx.x * blockDim.x + threadIdx.x;
    if (i >= n) return;
    out[i] = lrelu_f(in[i]);
}

// packed-input segment sums
__global__ void segsum_kernel(const unsigned* __restrict__ npk, const int* __restrict__ gid,
                              float* __restrict__ sn, int Nn) {
    size_t idx = (size_t)blockIdx.x * blockDim.x + threadIdx.x;
    if (idx >= (size_t)Nn * HD) return;
    size_t row = idx >> 7; int col = (int)(idx & 127);
    atomicAdd(&sn[(size_t)gid[row] * HD + col], unpack_f32(npk[idx]));
}

__global__ void seg_scale_sum_kernel(const unsigned* __restrict__ npk, const int* __restrict__ gid,
                                     const float* __restrict__ scale, float* __restrict__ out, int Nn) {
    size_t idx = (size_t)blockIdx.x * blockDim.x + threadIdx.x;
    if (idx >= (size_t)Nn * HD) return;
    size_t row = idx >> 7; int col = (int)(idx & 127);
    atomicAdd(&out[(size_t)gid[row] * HD + col], scale[row] * unpack_f32(npk[idx]));
}

__global__ void final_kernel(const float* __restrict__ sn, const float* __restrict__ Wp,
                             const float* __restrict__ bp, float* __restrict__ out, int G) {
    int g = (blockIdx.x * blockDim.x + threadIdx.x) >> 6;
    int lane = threadIdx.x & 63;
    if (g >= G) return;
    const float* r = sn + (size_t)g * HD;
    float p = r[lane] * Wp[lane] + r[lane + 64] * Wp[lane + 64];
#pragma unroll
    for (int off = 32; off > 0; off >>= 1) p += __shfl_down(p, off);
    if (lane == 0) out[g] = p + bp[0];
}

__global__ void canary_kernel(float* out, int n) {
    int i = blockIdx.x * blockDim.x + threadIdx.x;
    if (i < n) out[i] = 123.456f;
}

struct PkB { const short* hi; const short* lo; int KG; };

extern "C" void kernel_launch(void* const* d_in, const int* in_sizes, int n_in,
                              void* d_out, int out_size, void* d_ws, size_t ws_size,
                              hipStream_t stream) {
    const float* node = (const float*)d_in[0];
    const float* edge = (const float*)d_in[1];
    const int*   src  = (const int*)d_in[2];
    const int*   dst  = (const int*)d_in[3];
    const int*   gid  = (const int*)d_in[4];
    const float* Wn0  = (const float*)d_in[5];
    const float* bn0  = (const float*)d_in[6];
    const float* We0  = (const float*)d_in[7];
    const float* be0  = (const float*)d_in[8];
    const float* aWn  = (const float*)d_in[9];
    const float* abn  = (const float*)d_in[10];
    const float* aWe  = (const float*)d_in[11];
    const float* abe  = (const float*)d_in[12];
    const float* aWal = (const float*)d_in[13];
    const float* abal = (const float*)d_in[14];
    const float* aWat = (const float*)d_in[15];
    const float* abat = (const float*)d_in[16];
    const float* aWih = (const float*)d_in[17];
    const float* abih = (const float*)d_in[18];
    const float* aWhh = (const float*)d_in[19];
    const float* abhh = (const float*)d_in[20];
    const float* mWal = (const float*)d_in[21];
    const float* mbal = (const float*)d_in[22];
    const float* mWat = (const float*)d_in[23];
    const float* mbat = (const float*)d_in[24];
    const float* mWih = (const float*)d_in[25];
    const float* mbih = (const float*)d_in[26];
    const float* mWhh = (const float*)d_in[27];
    const float* mbhh = (const float*)d_in[28];
    const float* Wp   = (const float*)d_in[29];
    const float* bp   = (const float*)d_in[30];

    const int N = in_sizes[0] / 64;
    const int E = in_sizes[1] / 16;
    const int G = out_size;
    const int D = in_sizes[9] / (HD * HD);
    const int L = in_sizes[21] / (2 * HD);
    if (D > 8 || L > 4) return;

    char* wsb = (char*)d_ws;

    // ---- weight pre-pack (batched) ----
    short* pkcur = (short*)wsb;
    size_t elN;  // elems per matrix for current call
    auto packBn = [&](const float* B, int K, int ldb, int col0, int Ncols,
                      int nmat, size_t matB) -> PkB {
        int KG = 4 * ((K + 31) / 32);
        size_t elems = (size_t)(Ncols >> 4) * KG * 16 * 8;
        elN = elems;
        short* hi = pkcur; pkcur += elems * nmat;
        short* lo = pkcur; pkcur += elems * nmat;
        int total = (Ncols >> 4) * KG * 16;
        dim3 g((total + 255) / 256, nmat);
        pack_b_kernel<<<g, 256, 0, stream>>>(B, K, ldb, col0, Ncols, hi, lo, matB, elems);
        PkB p; p.hi = hi; p.lo = lo; p.KG = KG; return p;
    };
    PkB pWe0 = packBn(We0, 16, HD, 0, HD, 1, 0);
    PkB pWn0 = packBn(Wn0, 64, HD, 0, HD, 1, 0);
    PkB pAWn[8], pAWe[8], pAWat[8];
    {
        PkB b = packBn(aWn, HD, HD, 0, HD, D, (size_t)HD * HD);
        for (int d = 0; d < D; ++d) { pAWn[d] = b; pAWn[d].hi = b.hi + d * elN; pAWn[d].lo = b.lo + d * elN; }
        b = packBn(aWe, 2 * HD, HD, 0, HD, D, (size_t)2 * HD * HD);
        for (int d = 0; d < D; ++d) { pAWe[d] = b; pAWe[d].hi = b.hi + d * elN; pAWe[d].lo = b.lo + d * elN; }
        b = packBn(aWat, HD, HD, 0, HD, D, (size_t)HD * HD);
        for (int d = 0; d < D; ++d) { pAWat[d] = b; pAWat[d].hi = b.hi + d * elN; pAWat[d].lo = b.lo + d * elN; }
    }
    // GRU gates: one launch for all depths/slices
    short* ghiAll = pkcur; pkcur += (size_t)D * 6 * GRU_SL;
    short* gloAll = pkcur; pkcur += (size_t)D * 6 * GRU_SL;
    {
        int total = D * 6 * (GRU_SL / 8);
        pack_gru_kernel<<<(total + 255) / 256, 256, 0, stream>>>(aWih, aWhh, D, ghiAll, gloAll);
    }
    const short *gHi[8], *gLo[8];
    for (int d = 0; d < D; ++d) {
        gHi[d] = ghiAll + (size_t)d * 6 * GRU_SL;
        gLo[d] = gloAll + (size_t)d * 6 * GRU_SL;
    }
    PkB pMWat[4], pMWih[4], pMWhh[4];
    {
        PkB b = packBn(mWat, HD, HD, 0, HD, L, (size_t)HD * HD);
        for (int l = 0; l < L; ++l) { pMWat[l] = b; pMWat[l].hi = b.hi + l * elN; pMWat[l].lo = b.lo + l * elN; }
        b = packBn(mWih, HD, H3, 0, H3, L, (size_t)HD * H3);
        for (int l = 0; l < L; ++l) { pMWih[l] = b; pMWih[l].hi = b.hi + l * elN; pMWih[l].lo = b.lo + l * elN; }
        b = packBn(mWhh, HD, H3, 0, H3, L, (size_t)HD * H3);
        for (int l = 0; l < L; ++l) { pMWhh[l] = b; pMWhh[l].hi = b.hi + l * elN; pMWhh[l].lo = b.lo + l * elN; }
    }

    // ---- fixed workspace ----
    size_t off = ((size_t)((char*)pkcur - wsb) + 255) & ~(size_t)255;
    auto alloc = [&](size_t bytes) -> void* {
        void* p = (void*)(wsb + off);
        off += (bytes + 255) & ~(size_t)255;
        return p;
    };
    unsigned* npk = (unsigned*)alloc((size_t)N * HD * 4);  // node state n / S (dual)
    unsigned* hpk = (unsigned*)alloc((size_t)N * HD * 4);
    float* sc_e = (float*)alloc((size_t)E * 4);
    float* nmax = (float*)alloc((size_t)N * 4);
    float* nsum = (float*)alloc((size_t)N * 4);
    float* sc_n = (float*)alloc((size_t)N * 4);
    float* hd2  = (float*)alloc((size_t)N * 4);
    float* sn   = (float*)alloc((size_t)G * HD * 4);
    float* gmax = (float*)alloc((size_t)G * 4);
    float* gsum = (float*)alloc((size_t)G * 4);
    int* cnt    = (int*)alloc((size_t)(N + 1) * 4);
    int* rowptr = (int*)alloc((size_t)(N + 1) * 4);
    int* fillc  = (int*)alloc((size_t)N * 4);
    int* srcp   = (int*)alloc((size_t)E * 4);
    int* dstp   = (int*)alloc((size_t)E * 4);
    int* eidp   = (int*)alloc((size_t)E * 4);
    int* btot   = (int*)alloc(1024 * 4);

    // ---- overlay region OVR (msgpk | ctxpk | mol buffers) ----
    size_t ovr_off = off;
    size_t ctx_bytes = (size_t)N * HD * 4;
    size_t mol_bytes = 3 * ((size_t)G * HD * 4 + 256) + 2 * ((size_t)G * H3 * 4 + 256);
    size_t min_ovr = ctx_bytes > mol_bytes ? ctx_bytes : mol_bytes;
    int csr_mode, fullprec = 0;
    size_t mf = (size_t)E * HD * 4, mh = (size_t)E * HD * 2;
    if (ovr_off + (mf > min_ovr ? mf : min_ovr) <= ws_size) { csr_mode = 1; fullprec = 1; }
    else if (ovr_off + (mh > min_ovr ? mh : min_ovr) <= ws_size) { csr_mode = 1; fullprec = 0; }
    else if (ovr_off + min_ovr <= ws_size) { csr_mode = 0; }
    else {
        canary_kernel<<<(G + 255) / 256, 256, 0, stream>>>((float*)d_out, G);
        return;
    }
    void*     msgpk = (void*)(wsb + ovr_off);
    unsigned* ctxpk = (unsigned*)(wsb + ovr_off);
    size_t mo = ovr_off;
    auto molalloc = [&](size_t bytes) -> float* {
        float* p = (float*)(wsb + mo);
        mo += (bytes + 255) & ~(size_t)255;
        return p;
    };
    float* sbuf = molalloc((size_t)G * HD * 4);
    float* sctx = molalloc((size_t)G * HD * 4);
    float* Sg   = molalloc((size_t)G * HD * 4);
    float* gim  = molalloc((size_t)G * H3 * 4);
    float* ghm  = molalloc((size_t)G * H3 * 4);

    const int total_sc = N + 1;
    const int nb = (total_sc + 1023) / 1024;
    if (nb > 256) {  // CSR (needed by all paths now) impossible
        canary_kernel<<<(G + 255) / 256, 256, 0, stream>>>((float*)d_out, G);
        return;
    }

    auto mgemm = [&](const void* A, int K, const PkB& pk, const float* bias, void* C,
                     int M, int Nc, int act, const float* rdw, float* rdout,
                     const float* rowmask, int outpk, int apk) {
        dim3 g((M + 63) / 64, Nc / 64);
        mfma_gemm<<<g, dim3(256), 0, stream>>>((const float*)A, K, pk.hi, pk.lo, pk.KG,
                                               bias, (float*)C, M, Nc, act, rdw, rdout,
                                               rowmask, outpk, apk);
    };

    // ---- CSR build (dst constant across depths) ----
    hipMemsetAsync(cnt, 0, (size_t)(N + 1) * 4, stream);
    hipMemsetAsync(fillc, 0, (size_t)N * 4, stream);
    hist_kernel<<<(E + 255) / 256, 256, 0, stream>>>(dst, cnt, E);
    scan1_kernel<<<nb, 256, 0, stream>>>(cnt, rowptr, btot, total_sc);
    scan2_kernel<<<1, 256, 0, stream>>>(btot, nb);
    scan3_kernel<<<(total_sc + 255) / 256, 256, 0, stream>>>(rowptr, btot, total_sc);
    fill_kernel<<<(E + 255) / 256, 256, 0, stream>>>(src, dst, rowptr, fillc,
                                                     srcp, dstp, eidp, E);

    // ---- input embedding: n (packed) ----
    mgemm(node, 64, pWn0, bn0, npk, N, HD, 1, nullptr, nullptr, nullptr, 1, 0);

    // ---- atom-level message passing ----
    const int EB = (E + 63) / 64;
    for (int d = 0; d < D; ++d) {
        const float* bn_d  = abn  + (size_t)d * HD;
        const float* be_d  = abe  + (size_t)d * HD;
        const float* Wal_d = aWal + (size_t)d * 2 * HD;
        const float* bal_d = abal + d;
        const float* bat_d = abat + (size_t)d * HD;
        const float* bih_d = abih + (size_t)d * H3;
        const float* bhh_d = abhh + (size_t)d * H3;

        hipMemsetAsync(hd2, 0, (size_t)N * 4, stream);
        hipMemsetAsync(sc_e, 0, (size_t)E * 4, stream);
        // h = lrelu(n @ Wn + bn) -> packed; rowdot hd2 = h . Wal[128:256]
        mgemm(npk, HD, pAWn[d], bn_d, hpk, N, HD, 1, Wal_d + HD, hd2, nullptr, 1, 1);
        init_maxsum_kernel<<<(N + 255) / 256, 256, 0, stream>>>(nmax, nsum, N);
        // pass A (position order): score rowdot (+ sequential msg store)
        msg_pass_kernel<<<EB, 256, 0, stream>>>(hpk, srcp, dstp, eidp, edge,
                                                pWe0.hi, pWe0.lo, be0,
                                                pAWe[d].hi, pAWe[d].lo, be_d, Wal_d,
                                                sc_e, nullptr, msgpk, fullprec, E,
                                                csr_mode ? 0 : 1);
        score_combine_kernel<<<(E + 255) / 256, 256, 0, stream>>>(sc_e, hd2, dstp, bal_d, nmax, E);
        expsum_kernel<<<(E + 255) / 256, 256, 0, stream>>>(sc_e, nmax, nsum, dstp, E);
        attdiv_kernel<<<(E + 255) / 256, 256, 0, stream>>>(sc_e, nsum, dstp, E);
        if (csr_mode) {
            // S (npk, packed) = segsum(att * msg), contiguous
            ctx_gather_kernel<<<(N + 3) / 4, 256, 0, stream>>>(msgpk, sc_e, rowptr,
                                                               npk, N, fullprec);
        } else {
            // fallback: recompute msg, atomic f32 scatter into npk region
            hipMemsetAsync(npk, 0, (size_t)N * HD * 4, stream);
            msg_pass_kernel<<<EB, 256, 0, stream>>>(hpk, srcp, dstp, eidp, edge,
                                                    pWe0.hi, pWe0.lo, be0,
                                                    pAWe[d].hi, pAWe[d].lo, be_d, nullptr,
                                                    sc_e, (float*)npk, nullptr, 0, E, 2);
        }
        // ctx = elu(S @ Wat + bat) -> packed (OVR); empty rows -> 0
        mgemm(npk, HD, pAWat[d], bat_d, ctxpk, N, HD, 3, nullptr, nullptr, nsum, 1,
              csr_mode ? 1 : 0);
        // n = relu(GRU(ctx, h)) -> npk (packed)
        dim3 gg((N + 63) / 64, 2);
        gru_fused_kernel<<<gg, dim3(256), 0, stream>>>(ctxpk, hpk, gHi[d], gLo[d],
                                                       bih_d, bhh_d, npk, N);
    }

    // ---- molecule-level readout (mol buffers in OVR; ctxpk dead) ----
    hipMemsetAsync(sn, 0, (size_t)G * HD * 4, stream);
    segsum_kernel<<<((size_t)N * HD + 255) / 256, 256, 0, stream>>>(npk, gid, sn, N);
    for (int l = 0; l < L; ++l) {
        const float* Wal_l = mWal + (size_t)l * 2 * HD;
        const float* bal_l = mbal + l;
        const float* bat_l = mbat + (size_t)l * HD;
        const float* bih_l = mbih + (size_t)l * H3;
        const float* bhh_l = mbhh + (size_t)l * H3;

        lrelu_copy_kernel<<<((size_t)G * HD + 255) / 256, 256, 0, stream>>>(sn, sbuf, (size_t)G * HD);
        init_maxsum_kernel<<<(G + 255) / 256, 256, 0, stream>>>(gmax, gsum, G);
        score_kernel<<<(N + 3) / 4, 256, 0, stream>>>(npk, sbuf, gid, Wal_l, bal_l, sc_n, gmax, N);
        expsum_kernel<<<(N + 255) / 256, 256, 0, stream>>>(sc_n, gmax, gsum, gid, N);
        attdiv_kernel<<<(N + 255) / 256, 256, 0, stream>>>(sc_n, gsum, gid, N);
        hipMemsetAsync(Sg, 0, (size_t)G * HD * 4, stream);
        seg_scale_sum_kernel<<<((size_t)N * HD + 255) / 256, 256, 0, stream>>>(npk, gid, sc_n, Sg, N);
        mgemm(Sg, HD, pMWat[l], bat_l, sctx, G, HD, 3, nullptr, nullptr, gsum, 0, 0);
        mgemm(sctx, HD, pMWih[l], bih_l, gim, G, H3, 0, nullptr, nullptr, nullptr, 0, 0);
        mgemm(sbuf, HD, pMWhh[l], bhh_l, ghm, G, H3, 0, nullptr, nullptr, nullptr, 0, 0);
        gru_gate_kernel<<<((size_t)G * HD + 255) / 256, 256, 0, stream>>>(gim, ghm, sbuf, sn, G);
    }

    // ---- final prediction ----
    final_kernel<<<(G + 3) / 4, 256, 0, stream>>>(sn, Wp, bp, (float*)d_out, G);
}

// Round 15
// 1782.032 us; speedup vs baseline: 1.4206x; 1.0356x over previous
//
#include <hip/hip_runtime.h>
#include <hip/hip_bf16.h>
#include <math.h>

// AttentiveFP forward. Split-bf16 (3-term) MFMA engine.
//  - CSR-by-dst, position-ordered edges; msg stored at CSR slot; ctx =
//    contiguous gather (no atomics). Tiered msg storage + OVR overlay.
//  - softmax fused into msg_pass (no-max, shift-invariant); division folded
//    into ctx_gather / seg_scale_sum.
//  - e-tile in LDS as bf16-hi only (16KB -> high occupancy).
//  - activations packed u32 (bf16 hi|lo); fused GRU; batched weight packing.
// H=128, 3H=384.

#define HD 128
#define H3 384

typedef __attribute__((ext_vector_type(8))) short short8;
typedef __attribute__((ext_vector_type(4))) float f32x4;

__device__ __forceinline__ float lrelu_f(float x) { return x > 0.f ? x : 0.01f * x; }
__device__ __forceinline__ float sigmoid_f(float x) { return 1.f / (1.f + expf(-x)); }

__device__ __forceinline__ unsigned short bf16_rne(float v, float* back) {
    unsigned u = __float_as_uint(v);
    unsigned r = (u + 0x7FFFu + ((u >> 16) & 1u)) >> 16;
    *back = __uint_as_float(r << 16);
    return (unsigned short)r;
}

__device__ __forceinline__ unsigned pack_hl(float v) {
    float back, d;
    unsigned short h = bf16_rne(v, &back);
    unsigned short l = bf16_rne(v - back, &d);
    return ((unsigned)h << 16) | (unsigned)l;
}
__device__ __forceinline__ float unpack_f32(unsigned w) {
    return __uint_as_float(w & 0xffff0000u) + __uint_as_float(w << 16);
}

__device__ __forceinline__ void split8(const float* p, short8& h8, short8& l8) {
    float4 u0 = *reinterpret_cast<const float4*>(p);
    float4 u1 = *reinterpret_cast<const float4*>(p + 4);
    float vv[8] = {u0.x, u0.y, u0.z, u0.w, u1.x, u1.y, u1.z, u1.w};
#pragma unroll
    for (int j = 0; j < 8; ++j) {
        float back, d;
        h8[j] = (short)bf16_rne(vv[j], &back);
        l8[j] = (short)bf16_rne(vv[j] - back, &d);
    }
}

__device__ __forceinline__ void unpack8(const unsigned* p, short8& h8, short8& l8) {
    uint4 w0 = *reinterpret_cast<const uint4*>(p);
    uint4 w1 = *reinterpret_cast<const uint4*>(p + 4);
    unsigned ww[8] = {w0.x, w0.y, w0.z, w0.w, w1.x, w1.y, w1.z, w1.w};
#pragma unroll
    for (int j = 0; j < 8; ++j) {
        h8[j] = (short)(ww[j] >> 16);
        l8[j] = (short)(ww[j] & 0xffffu);
    }
}

// ---------------------------------------------------------------------------
// Batched pack: blockIdx.y = matrix index. Layout [nblk][kg][col16][e8].
// ---------------------------------------------------------------------------
__global__ void pack_b_kernel(const float* __restrict__ B, int K, int ldb, int col0,
                              int Ncols, short* __restrict__ hi, short* __restrict__ lo,
                              size_t matB, size_t matO) {
    int KG = 4 * ((K + 31) / 32);
    int mat = blockIdx.y;
    B += (size_t)mat * matB;
    hi += (size_t)mat * matO;
    lo += (size_t)mat * matO;
    int idx = blockIdx.x * blockDim.x + threadIdx.x;
    int total = (Ncols >> 4) * KG * 16;
    if (idx >= total) return;
    int col = idx & 15;
    int kg = (idx >> 4) % KG;
    int nblk = idx / (16 * KG);
    size_t o = (size_t)idx * 8;
#pragma unroll
    for (int e = 0; e < 8; ++e) {
        int k = kg * 8 + e;
        float v = (k < K) ? B[(size_t)k * ldb + col0 + nblk * 16 + col] : 0.f;
        float hf, d;
        unsigned short h = bf16_rne(v, &hf);
        unsigned short l = bf16_rne(v - hf, &d);
        hi[o + e] = (short)h;
        lo[o + e] = (short)l;
    }
}

#define GRU_SL (8 * 16 * 16 * 8)
__global__ void pack_gru_kernel(const float* __restrict__ Wih, const float* __restrict__ Whh,
                                int D, short* __restrict__ hi, short* __restrict__ lo) {
    const int per = 6 * (GRU_SL / 8);
    int idx = blockIdx.x * blockDim.x + threadIdx.x;
    if (idx >= D * per) return;
    int d = idx / per;
    int r = idx % per;
    int s = r / (GRU_SL / 8);
    int g8 = r % (GRU_SL / 8);
    int col = g8 & 15;
    int kg = (g8 >> 4) & 15;
    int nblk = g8 >> 8;
    const float* B = (s < 3 ? Wih : Whh) + (size_t)d * HD * H3;
    int col0 = (s % 3) * HD;
    size_t o = (size_t)idx * 8;
#pragma unroll
    for (int e = 0; e < 8; ++e) {
        int k = kg * 8 + e;
        float v = B[(size_t)k * H3 + col0 + nblk * 16 + col];
        float hf, d2;
        unsigned short h = bf16_rne(v, &hf);
        unsigned short l = bf16_rne(v - hf, &d2);
        hi[o + e] = (short)h;
        lo[o + e] = (short)l;
    }
}

// ---------------------------------------------------------------------------
// Generic split-bf16 GEMM (apk/outpk/rowdot/rowmask).
// ---------------------------------------------------------------------------
__global__ __launch_bounds__(256) void mfma_gemm(
    const float* __restrict__ A, int K,
    const short* __restrict__ Bhi, const short* __restrict__ Blo, int KG,
    const float* __restrict__ bias, float* __restrict__ C, int M, int N, int act,
    const float* __restrict__ rdw, float* __restrict__ rdout,
    const float* __restrict__ rowmask, int outpk, int apk)
{
    const int t = threadIdx.x, lane = t & 63, w = t >> 6;
    const int wm = w & 1, wn = w >> 1, q = lane >> 4, r16 = lane & 15;
    const int m0 = blockIdx.x * 64, n0 = blockIdx.y * 64;
    const int KT = K >> 5;

    f32x4 acc[2][2];
#pragma unroll
    for (int a = 0; a < 2; ++a)
#pragma unroll
        for (int b = 0; b < 2; ++b) { acc[a][b][0]=0.f; acc[a][b][1]=0.f; acc[a][b][2]=0.f; acc[a][b][3]=0.f; }

    int arow[2];
#pragma unroll
    for (int mt = 0; mt < 2; ++mt) {
        int m = m0 + (wm << 5) + (mt << 4) + r16;
        arow[mt] = (m >= M) ? M - 1 : m;
    }

    for (int kt = 0; kt < KT; ++kt) {
        short8 ah[2], al[2];
#pragma unroll
        for (int mt = 0; mt < 2; ++mt) {
            size_t aoff = (size_t)arow[mt] * K + (kt << 5) + (q << 3);
            if (apk) unpack8((const unsigned*)A + aoff, ah[mt], al[mt]);
            else split8(A + aoff, ah[mt], al[mt]);
        }
        const int kg = (kt << 2) + q;
#pragma unroll
        for (int nt = 0; nt < 2; ++nt) {
            int nblk = (n0 >> 4) + (wn << 1) + nt;
            size_t boff = (((size_t)nblk * KG + kg) * 16 + r16) * 8;
            short8 bh = *reinterpret_cast<const short8*>(Bhi + boff);
            short8 bl = *reinterpret_cast<const short8*>(Blo + boff);
#pragma unroll
            for (int mt = 0; mt < 2; ++mt) {
                acc[mt][nt] = __builtin_amdgcn_mfma_f32_16x16x32_bf16(ah[mt], bh, acc[mt][nt], 0, 0, 0);
                acc[mt][nt] = __builtin_amdgcn_mfma_f32_16x16x32_bf16(ah[mt], bl, acc[mt][nt], 0, 0, 0);
                acc[mt][nt] = __builtin_amdgcn_mfma_f32_16x16x32_bf16(al[mt], bh, acc[mt][nt], 0, 0, 0);
            }
        }
    }

#pragma unroll
    for (int mt = 0; mt < 2; ++mt) {
        float pv[4] = {0.f, 0.f, 0.f, 0.f};
#pragma unroll
        for (int nt = 0; nt < 2; ++nt) {
            int col = n0 + (wn << 5) + (nt << 4) + r16;
            float bi = bias ? bias[col] : 0.f;
            float wc = rdw ? rdw[col] : 0.f;
#pragma unroll
            for (int i = 0; i < 4; ++i) {
                int m = m0 + (wm << 5) + (mt << 4) + (q << 2) + i;
                float v = acc[mt][nt][i] + bi;
                if (act == 1) v = v > 0.f ? v : 0.01f * v;
                else if (act == 2) v = fmaxf(v, 0.f);
                else if (act == 3) v = v > 0.f ? v : expf(v) - 1.f;
                if (rowmask && m < M && rowmask[m] == 0.f) v = 0.f;
                pv[i] += wc * v;
                if (m < M) {
                    if (outpk) ((unsigned*)C)[(size_t)m * N + col] = pack_hl(v);
                    else C[(size_t)m * N + col] = v;
                }
            }
        }
        if (rdw) {
#pragma unroll
            for (int i = 0; i < 4; ++i) {
                float p = pv[i];
                p += __shfl_xor(p, 1); p += __shfl_xor(p, 2);
                p += __shfl_xor(p, 4); p += __shfl_xor(p, 8);
                int m = m0 + (wm << 5) + (mt << 4) + (q << 2) + i;
                if (r16 == 0 && m < M) atomicAdd(&rdout[m], p);
            }
        }
    }
}

// ---------------------------------------------------------------------------
// Fused edge kernel, position-ordered, FUSED SOFTMAX (no-max).
// e tile in LDS as bf16-hi only (16KB). Stage 2 e-half uses 2 MFMAs (lo=0).
// mode 0: msg store + score: sc[m]=exp(lrelu(dot+hd2[dst]+bal)), nsum[dst]+=
// mode 1: score only (fallback A)   mode 2: scatter S += (sc[m]/nsum[dst])*msg
// ---------------------------------------------------------------------------
__global__ __launch_bounds__(256) void msg_pass_kernel(
    const unsigned* __restrict__ hpk, const int* __restrict__ srcp,
    const int* __restrict__ dstp, const int* __restrict__ eidp,
    const float* __restrict__ edge,
    const short* __restrict__ W0hi, const short* __restrict__ W0lo,
    const float* __restrict__ be0,
    const short* __restrict__ Wehi, const short* __restrict__ Welo,
    const float* __restrict__ be,
    const float* __restrict__ wal, const float* __restrict__ hd2,
    const float* __restrict__ bal,
    float* __restrict__ sc, float* __restrict__ nsum, float* __restrict__ S,
    void* __restrict__ msgpk, int fullprec,
    int E, int mode)
{
    __shared__ unsigned short elds[64 * 128];  // e tile, bf16 hi only
    __shared__ float sred[64];                 // cross-wave dot halves
    const int t = threadIdx.x, lane = t & 63, w = t >> 6;
    const int wm = w & 1, wn = w >> 1, q = lane >> 4, r16 = lane & 15;
    const int e0 = blockIdx.x * 64;

    // ---- stage 1: e tile ----
    {
        f32x4 ea[2][4];
#pragma unroll
        for (int a = 0; a < 2; ++a)
#pragma unroll
            for (int b = 0; b < 4; ++b) { ea[a][b][0]=0.f; ea[a][b][1]=0.f; ea[a][b][2]=0.f; ea[a][b][3]=0.f; }
        short8 eah[2], eal[2];
#pragma unroll
        for (int mt = 0; mt < 2; ++mt) {
            int er = e0 + (wm << 5) + (mt << 4) + r16;
            if (er >= E) er = E - 1;
            int eid = eidp[er];
            if (q < 2) split8(edge + (size_t)eid * 16 + (q << 3), eah[mt], eal[mt]);
            else {
#pragma unroll
                for (int j = 0; j < 8; ++j) { eah[mt][j] = 0; eal[mt][j] = 0; }
            }
        }
#pragma unroll
        for (int nt = 0; nt < 4; ++nt) {
            int nblk = (wn << 2) + nt;
            size_t boff = (((size_t)nblk * 4 + q) * 16 + r16) * 8;
            short8 bh = *reinterpret_cast<const short8*>(W0hi + boff);
            short8 bl = *reinterpret_cast<const short8*>(W0lo + boff);
#pragma unroll
            for (int mt = 0; mt < 2; ++mt) {
                ea[mt][nt] = __builtin_amdgcn_mfma_f32_16x16x32_bf16(eah[mt], bh, ea[mt][nt], 0, 0, 0);
                ea[mt][nt] = __builtin_amdgcn_mfma_f32_16x16x32_bf16(eah[mt], bl, ea[mt][nt], 0, 0, 0);
                ea[mt][nt] = __builtin_amdgcn_mfma_f32_16x16x32_bf16(eal[mt], bh, ea[mt][nt], 0, 0, 0);
            }
        }
#pragma unroll
        for (int mt = 0; mt < 2; ++mt)
#pragma unroll
            for (int nt = 0; nt < 4; ++nt) {
                int col = (wn << 6) + (nt << 4) + r16;
#pragma unroll
                for (int i = 0; i < 4; ++i) {
                    int row = (wm << 5) + (mt << 4) + (q << 2) + i;
                    float v = lrelu_f(ea[mt][nt][i] + be0[col]);
                    float b_;
                    elds[row * 128 + (col ^ ((row & 7) << 3))] = bf16_rne(v, &b_);
                }
            }
    }
    __syncthreads();

    // ---- stage 2: msg ----
    f32x4 acc[2][4];
#pragma unroll
    for (int a = 0; a < 2; ++a)
#pragma unroll
        for (int b = 0; b < 4; ++b) { acc[a][b][0]=0.f; acc[a][b][1]=0.f; acc[a][b][2]=0.f; acc[a][b][3]=0.f; }
    int grow[2], arw[2];
#pragma unroll
    for (int mt = 0; mt < 2; ++mt) {
        int m = e0 + (wm << 5) + (mt << 4) + r16;
        if (m >= E) m = E - 1;
        grow[mt] = srcp[m];
        arw[mt] = (wm << 5) + (mt << 4) + r16;
    }
#pragma unroll
    for (int kt = 0; kt < 8; ++kt) {
        short8 ah[2], al[2];
        const bool ehalf = (kt >= 4);
#pragma unroll
        for (int mt = 0; mt < 2; ++mt) {
            if (!ehalf) {
                unpack8(hpk + (size_t)grow[mt] * HD + (kt << 5) + (q << 3), ah[mt], al[mt]);
            } else {
                int row = arw[mt];
                int sh = (row & 7) << 3;
                int c = ((kt - 4) << 5) + (q << 3);
                uint4 wv = *reinterpret_cast<const uint4*>(&elds[row * 128 + (c ^ sh)]);
                unsigned ww[4] = {wv.x, wv.y, wv.z, wv.w};
#pragma unroll
                for (int j = 0; j < 4; ++j) {
                    ah[mt][2 * j]     = (short)(ww[j] & 0xffffu);
                    ah[mt][2 * j + 1] = (short)(ww[j] >> 16);
                    al[mt][2 * j] = 0; al[mt][2 * j + 1] = 0;
                }
            }
        }
        const int kg = (kt << 2) + q;
#pragma unroll
        for (int nt = 0; nt < 4; ++nt) {
            int nblk = (wn << 2) + nt;
            size_t boff = (((size_t)nblk * 32 + kg) * 16 + r16) * 8;
            short8 bh = *reinterpret_cast<const short8*>(Wehi + boff);
            short8 bl = *reinterpret_cast<const short8*>(Welo + boff);
#pragma unroll
            for (int mt = 0; mt < 2; ++mt) {
                acc[mt][nt] = __builtin_amdgcn_mfma_f32_16x16x32_bf16(ah[mt], bh, acc[mt][nt], 0, 0, 0);
                acc[mt][nt] = __builtin_amdgcn_mfma_f32_16x16x32_bf16(ah[mt], bl, acc[mt][nt], 0, 0, 0);
                if (!ehalf)
                    acc[mt][nt] = __builtin_amdgcn_mfma_f32_16x16x32_bf16(al[mt], bh, acc[mt][nt], 0, 0, 0);
            }
        }
    }

    if (mode == 2) {
#pragma unroll
        for (int mt = 0; mt < 2; ++mt)
#pragma unroll
            for (int i = 0; i < 4; ++i) {
                int m = e0 + (wm << 5) + (mt << 4) + (q << 2) + i;
                if (m >= E) continue;
                int dn = dstp[m];
                float s = nsum[dn];
                float a = (s > 0.f) ? sc[m] / s : 0.f;
#pragma unroll
                for (int nt = 0; nt < 4; ++nt) {
                    int col = (wn << 6) + (nt << 4) + r16;
                    float v = lrelu_f(acc[mt][nt][i] + be[col]);
                    atomicAdd(&S[(size_t)dn * HD + col], a * v);
                }
            }
        return;
    }

    // mode 0/1: msg store (mode 0) + fused score/exp/sum
    float pv[2][4];
#pragma unroll
    for (int mt = 0; mt < 2; ++mt) {
#pragma unroll
        for (int i = 0; i < 4; ++i) pv[mt][i] = 0.f;
#pragma unroll
        for (int i = 0; i < 4; ++i) {
            int m = e0 + (wm << 5) + (mt << 4) + (q << 2) + i;
#pragma unroll
            for (int nt = 0; nt < 4; ++nt) {
                int col = (wn << 6) + (nt << 4) + r16;
                float v = lrelu_f(acc[mt][nt][i] + be[col]);
                pv[mt][i] += wal[col] * v;
                if (mode == 0 && m < E) {
                    size_t ro = (size_t)m * HD + col;
                    if (fullprec) ((unsigned*)msgpk)[ro] = pack_hl(v);
                    else { float b_; ((unsigned short*)msgpk)[ro] = bf16_rne(v, &b_); }
                }
            }
        }
#pragma unroll
        for (int i = 0; i < 4; ++i) {
            float p = pv[mt][i];
            p += __shfl_xor(p, 1); p += __shfl_xor(p, 2);
            p += __shfl_xor(p, 4); p += __shfl_xor(p, 8);
            pv[mt][i] = p;
        }
    }
    if (wn == 0 && r16 == 0) {
#pragma unroll
        for (int mt = 0; mt < 2; ++mt)
#pragma unroll
            for (int i = 0; i < 4; ++i)
                sred[(wm << 5) + (mt << 4) + (q << 2) + i] = pv[mt][i];
    }
    __syncthreads();
    if (wn == 1 && r16 == 0) {
#pragma unroll
        for (int mt = 0; mt < 2; ++mt)
#pragma unroll
            for (int i = 0; i < 4; ++i) {
                int row = (wm << 5) + (mt << 4) + (q << 2) + i;
                int m = e0 + row;
                if (m < E) {
                    int dm = dstp[m];
                    float v = lrelu_f(pv[mt][i] + sred[row] + hd2[dm] + bal[0]);
                    float e = expf(v);
                    sc[m] = e;
                    atomicAdd(&nsum[dm], e);
                }
            }
    }
}

// ---------------------------------------------------------------------------
// ctx gather: one wave per node; divides by nsum[wid]. Writes PACKED S.
// ---------------------------------------------------------------------------
__global__ __launch_bounds__(256) void ctx_gather_kernel(
    const void* __restrict__ msgpk, const float* __restrict__ sc,
    const float* __restrict__ nsum, const int* __restrict__ rowptr,
    unsigned* __restrict__ Spk, int Nn, int fullprec)
{
    int wid = (blockIdx.x * blockDim.x + threadIdx.x) >> 6;
    int lane = threadIdx.x & 63;
    if (wid >= Nn) return;
    int p0 = rowptr[wid], p1 = rowptr[wid + 1];
    float s = nsum[wid];
    float inv = (s > 0.f) ? 1.f / s : 0.f;
    float a0 = 0.f, a1 = 0.f;
    if (fullprec) {
        const unsigned* mp = (const unsigned*)msgpk;
        for (int p = p0; p < p1; ++p) {
            float a = sc[p] * inv;
            uint2 w = *reinterpret_cast<const uint2*>(mp + (size_t)p * HD + lane * 2);
            a0 += a * unpack_f32(w.x);
            a1 += a * unpack_f32(w.y);
        }
    } else {
        const unsigned short* mp = (const unsigned short*)msgpk;
        for (int p = p0; p < p1; ++p) {
            float a = sc[p] * inv;
            unsigned w = *reinterpret_cast<const unsigned*>(mp + (size_t)p * HD + lane * 2);
            a0 += a * __uint_as_float(w << 16);
            a1 += a * __uint_as_float(w & 0xffff0000u);
        }
    }
    Spk[(size_t)wid * HD + lane * 2] = pack_hl(a0);
    Spk[(size_t)wid * HD + lane * 2 + 1] = pack_hl(a1);
}

// ---- CSR build ----
__global__ void hist_kernel(const int* __restrict__ dst, int* __restrict__ cnt, int E) {
    int i = blockIdx.x * blockDim.x + threadIdx.x;
    if (i < E) atomicAdd(&cnt[dst[i]], 1);
}
__global__ void scan1_kernel(const int* __restrict__ cnt, int* __restrict__ pre,
                             int* __restrict__ btot, int total) {
    __shared__ int ts[256];
    int base = blockIdx.x * 1024;
    int c[4], tsum = 0;
#pragma unroll
    for (int j = 0; j < 4; ++j) {
        int idx = base + threadIdx.x * 4 + j;
        c[j] = (idx < total) ? cnt[idx] : 0;
        tsum += c[j];
    }
    ts[threadIdx.x] = tsum;
    __syncthreads();
    for (int off = 1; off < 256; off <<= 1) {
        int v = (threadIdx.x >= off) ? ts[threadIdx.x - off] : 0;
        __syncthreads();
        ts[threadIdx.x] += v;
        __syncthreads();
    }
    int run = ts[threadIdx.x] - tsum;
#pragma unroll
    for (int j = 0; j < 4; ++j) {
        int idx = base + threadIdx.x * 4 + j;
        if (idx < total) pre[idx] = run;
        run += c[j];
    }
    if (threadIdx.x == 255) btot[blockIdx.x] = ts[255];
}
__global__ void scan2_kernel(int* __restrict__ btot, int nb) {
    __shared__ int ts[256];
    int v = (threadIdx.x < nb) ? btot[threadIdx.x] : 0;
    ts[threadIdx.x] = v;
    __syncthreads();
    for (int off = 1; off < 256; off <<= 1) {
        int u = (threadIdx.x >= off) ? ts[threadIdx.x - off] : 0;
        __syncthreads();
        ts[threadIdx.x] += u;
        __syncthreads();
    }
    if (threadIdx.x < nb) btot[threadIdx.x] = ts[threadIdx.x] - v;
}
__global__ void scan3_kernel(int* __restrict__ pre, const int* __restrict__ btot, int total) {
    int i = blockIdx.x * blockDim.x + threadIdx.x;
    if (i < total) pre[i] += btot[i >> 10];
}
__global__ void fill_kernel(const int* __restrict__ src, const int* __restrict__ dst,
                            const int* __restrict__ rowptr, int* __restrict__ fillc,
                            int* __restrict__ srcp, int* __restrict__ dstp,
                            int* __restrict__ eidp, int E) {
    int i = blockIdx.x * blockDim.x + threadIdx.x;
    if (i >= E) return;
    int d = dst[i];
    int pos = rowptr[d] + atomicAdd(&fillc[d], 1);
    srcp[pos] = src[i];
    dstp[pos] = d;
    eidp[pos] = i;
}

// ---------------------------------------------------------------------------
// Fused GRU -> packed npk.
// ---------------------------------------------------------------------------
__global__ __launch_bounds__(256) void gru_fused_kernel(
    const unsigned* __restrict__ ctxpk, const unsigned* __restrict__ hpk,
    const short* __restrict__ ghi, const short* __restrict__ glo,
    const float* __restrict__ bih, const float* __restrict__ bhh,
    unsigned* __restrict__ out, int M)
{
    const int t = threadIdx.x, lane = t & 63, w = t >> 6;
    const int wm = w & 1, wn = w >> 1, q = lane >> 4, r16 = lane & 15;
    const int m0 = blockIdx.x * 64, j0 = blockIdx.y * 64;

    f32x4 acc[6][2][2];
#pragma unroll
    for (int g = 0; g < 6; ++g)
#pragma unroll
        for (int a = 0; a < 2; ++a)
#pragma unroll
            for (int b = 0; b < 2; ++b) { acc[g][a][b][0]=0.f; acc[g][a][b][1]=0.f; acc[g][a][b][2]=0.f; acc[g][a][b][3]=0.f; }

    int arow[2];
#pragma unroll
    for (int mt = 0; mt < 2; ++mt) {
        int m = m0 + (wm << 5) + (mt << 4) + r16;
        arow[mt] = (m >= M) ? M - 1 : m;
    }

#pragma unroll
    for (int kt = 0; kt < 4; ++kt) {
        short8 ah[2], al[2];
#pragma unroll
        for (int mt = 0; mt < 2; ++mt)
            unpack8(ctxpk + (size_t)arow[mt] * HD + (kt << 5) + (q << 3), ah[mt], al[mt]);
        const int kg = (kt << 2) + q;
#pragma unroll
        for (int g = 0; g < 3; ++g)
#pragma unroll
            for (int nt = 0; nt < 2; ++nt) {
                int nblk = (j0 >> 4) + (wn << 1) + nt;
                size_t boff = (size_t)g * GRU_SL + (((size_t)nblk * 16 + kg) * 16 + r16) * 8;
                short8 bh = *reinterpret_cast<const short8*>(ghi + boff);
                short8 bl = *reinterpret_cast<const short8*>(glo + boff);
#pragma unroll
                for (int mt = 0; mt < 2; ++mt) {
                    acc[g][mt][nt] = __builtin_amdgcn_mfma_f32_16x16x32_bf16(ah[mt], bh, acc[g][mt][nt], 0, 0, 0);
                    acc[g][mt][nt] = __builtin_amdgcn_mfma_f32_16x16x32_bf16(ah[mt], bl, acc[g][mt][nt], 0, 0, 0);
                    acc[g][mt][nt] = __builtin_amdgcn_mfma_f32_16x16x32_bf16(al[mt], bh, acc[g][mt][nt], 0, 0, 0);
                }
            }
    }
#pragma unroll
    for (int kt = 0; kt < 4; ++kt) {
        short8 ah[2], al[2];
#pragma unroll
        for (int mt = 0; mt < 2; ++mt)
            unpack8(hpk + (size_t)arow[mt] * HD + (kt << 5) + (q << 3), ah[mt], al[mt]);
        const int kg = (kt << 2) + q;
#pragma unroll
        for (int g = 3; g < 6; ++g)
#pragma unroll
            for (int nt = 0; nt < 2; ++nt) {
                int nblk = (j0 >> 4) + (wn << 1) + nt;
                size_t boff = (size_t)g * GRU_SL + (((size_t)nblk * 16 + kg) * 16 + r16) * 8;
                short8 bh = *reinterpret_cast<const short8*>(ghi + boff);
                short8 bl = *reinterpret_cast<const short8*>(glo + boff);
#pragma unroll
                for (int mt = 0; mt < 2; ++mt) {
                    acc[g][mt][nt] = __builtin_amdgcn_mfma_f32_16x16x32_bf16(ah[mt], bh, acc[g][mt][nt], 0, 0, 0);
                    acc[g][mt][nt] = __builtin_amdgcn_mfma_f32_16x16x32_bf16(ah[mt], bl, acc[g][mt][nt], 0, 0, 0);
                    acc[g][mt][nt] = __builtin_amdgcn_mfma_f32_16x16x32_bf16(al[mt], bh, acc[g][mt][nt], 0, 0, 0);
                }
            }
    }

#pragma unroll
    for (int mt = 0; mt < 2; ++mt)
#pragma unroll
        for (int nt = 0; nt < 2; ++nt) {
            int j = j0 + (wn << 5) + (nt << 4) + r16;
            float bir = bih[j], biz = bih[HD + j], bin = bih[2 * HD + j];
            float bhr = bhh[j], bhz = bhh[HD + j], bhn = bhh[2 * HD + j];
#pragma unroll
            for (int i = 0; i < 4; ++i) {
                int m = m0 + (wm << 5) + (mt << 4) + (q << 2) + i;
                if (m >= M) continue;
                float r = sigmoid_f(acc[0][mt][nt][i] + bir + acc[3][mt][nt][i] + bhr);
                float z = sigmoid_f(acc[1][mt][nt][i] + biz + acc[4][mt][nt][i] + bhz);
                float hn = acc[5][mt][nt][i] + bhn;
                float nn = tanhf(acc[2][mt][nt][i] + bin + r * hn);
                float hv = unpack_f32(hpk[(size_t)m * HD + j]);
                out[(size_t)m * HD + j] = pack_hl(fmaxf((1.f - z) * nn + z * hv, 0.f));
            }
        }
}

// mol-phase score, fused exp + sum (no max)
__global__ __launch_bounds__(256) void score_kernel(
    const unsigned* __restrict__ Apk, const float* __restrict__ B,
    const int* __restrict__ seg, const float* __restrict__ w,
    const float* __restrict__ bal, float* __restrict__ out,
    float* __restrict__ sumbuf, int count)
{
    int i = (blockIdx.x * blockDim.x + threadIdx.x) >> 6;
    int lane = threadIdx.x & 63;
    if (i >= count) return;
    int s = seg[i];
    float a0 = unpack_f32(Apk[(size_t)i * HD + lane]);
    float a1 = unpack_f32(Apk[(size_t)i * HD + lane + 64]);
    const float* br = B + (size_t)s * HD;
    float p = a0 * w[lane] + a1 * w[lane + 64]
            + br[lane] * w[128 + lane] + br[lane + 64] * w[192 + lane];
#pragma unroll
    for (int off = 32; off > 0; off >>= 1) p += __shfl_down(p, off);
    if (lane == 0) {
        float e = expf(lrelu_f(p + bal[0]));
        out[i] = e;
        atomicAdd(&sumbuf[s], e);
    }
}

__global__ void gru_gate_kernel(const float* __restrict__ gi, const float* __restrict__ gh,
                                const float* __restrict__ h, float* __restrict__ out, int M) {
    size_t idx = (size_t)blockIdx.x * blockDim.x + threadIdx.x;
    if (idx >= (size_t)M * HD) return;
    size_t row = idx >> 7; int col = (int)(idx & 127);
    const float* gir = gi + row * H3;
    const float* ghr = gh + row * H3;
    float r = sigmoid_f(gir[col] + ghr[col]);
    float z = sigmoid_f(gir[col + 128] + ghr[col + 128]);
    float nn = tanhf(gir[col + 256] + r * ghr[col + 256]);
    float o = (1.f - z) * nn + z * h[idx];
    out[idx] = fmaxf(o, 0.f);
}

__global__ void lrelu_copy_kernel(const float* __restrict__ in, float* __restrict__ out, size_t n) {
    size_t i = (size_t)blockIdx.x * blockDim.x + threadIdx.x;
    if (i >= n) return;
    out[i] = lrelu_f(in[i]);
}

__global__ void segsum_kernel(const unsigned* __restrict__ npk, const int* __restrict__ gid,
                              float* __restrict__ sn, int Nn) {
    size_t idx = (size_t)blockIdx.x * blockDim.x + threadIdx.x;
    if (idx >= (size_t)Nn * HD) return;
    size_t row = idx >> 7; int col = (int)(idx & 127);
    atomicAdd(&sn[(size_t)gid[row] * HD + col], unpack_f32(npk[idx]));
}

// seg scale-sum with division by per-graph sum folded in
__global__ void seg_scale_sum_kernel(const unsigned* __restrict__ npk, const int* __restrict__ gid,
                                     const float* __restrict__ scale, const float* __restrict__ gsum,
                                     float* __restrict__ out, int Nn) {
    size_t idx = (size_t)blockIdx.x * blockDim.x + threadIdx.x;
    if (idx >= (size_t)Nn * HD) return;
    size_t row = idx >> 7; int col = (int)(idx & 127);
    int g = gid[row];
    float s = gsum[g];
    float a = (s > 0.f) ? scale[row] / s : 0.f;
    atomicAdd(&out[(size_t)g * HD + col], a * unpack_f32(npk[idx]));
}

__global__ void final_kernel(const float* __restrict__ sn, const float* __restrict__ Wp,
                             const float* __restrict__ bp, float* __restrict__ out, int G) {
    int g = (blockIdx.x * blockDim.x + threadIdx.x) >> 6;
    int lane = threadIdx.x & 63;
    if (g >= G) return;
    const float* r = sn + (size_t)g * HD;
    float p = r[lane] * Wp[lane] + r[lane + 64] * Wp[lane + 64];
#pragma unroll
    for (int off = 32; off > 0; off >>= 1) p += __shfl_down(p, off);
    if (lane == 0) out[g] = p + bp[0];
}

__global__ void canary_kernel(float* out, int n) {
    int i = blockIdx.x * blockDim.x + threadIdx.x;
    if (i < n) out[i] = 123.456f;
}

struct PkB { const short* hi; const short* lo; int KG; };

extern "C" void kernel_launch(void* const* d_in, const int* in_sizes, int n_in,
                              void* d_out, int out_size, void* d_ws, size_t ws_size,
                              hipStream_t stream) {
    const float* node = (const float*)d_in[0];
    const float* edge = (const float*)d_in[1];
    const int*   src  = (const int*)d_in[2];
    const int*   dst  = (const int*)d_in[3];
    const int*   gid  = (const int*)d_in[4];
    const float* Wn0  = (const float*)d_in[5];
    const float* bn0  = (const float*)d_in[6];
    const float* We0  = (const float*)d_in[7];
    const float* be0  = (const float*)d_in[8];
    const float* aWn  = (const float*)d_in[9];
    const float* abn  = (const float*)d_in[10];
    const float* aWe  = (const float*)d_in[11];
    const float* abe  = (const float*)d_in[12];
    const float* aWal = (const float*)d_in[13];
    const float* abal = (const float*)d_in[14];
    const float* aWat = (const float*)d_in[15];
    const float* abat = (const float*)d_in[16];
    const float* aWih = (const float*)d_in[17];
    const float* abih = (const float*)d_in[18];
    const float* aWhh = (const float*)d_in[19];
    const float* abhh = (const float*)d_in[20];
    const float* mWal = (const float*)d_in[21];
    const float* mbal = (const float*)d_in[22];
    const float* mWat = (const float*)d_in[23];
    const float* mbat = (const float*)d_in[24];
    const float* mWih = (const float*)d_in[25];
    const float* mbih = (const float*)d_in[26];
    const float* mWhh = (const float*)d_in[27];
    const float* mbhh = (const float*)d_in[28];
    const float* Wp   = (const float*)d_in[29];
    const float* bp   = (const float*)d_in[30];

    const int N = in_sizes[0] / 64;
    const int E = in_sizes[1] / 16;
    const int G = out_size;
    const int D = in_sizes[9] / (HD * HD);
    const int L = in_sizes[21] / (2 * HD);
    if (D > 8 || L > 4) return;

    char* wsb = (char*)d_ws;

    // ---- weight pre-pack (batched) ----
    short* pkcur = (short*)wsb;
    size_t elN;
    auto packBn = [&](const float* B, int K, int ldb, int col0, int Ncols,
                      int nmat, size_t matB) -> PkB {
        int KG = 4 * ((K + 31) / 32);
        size_t elems = (size_t)(Ncols >> 4) * KG * 16 * 8;
        elN = elems;
        short* hi = pkcur; pkcur += elems * nmat;
        short* lo = pkcur; pkcur += elems * nmat;
        int total = (Ncols >> 4) * KG * 16;
        dim3 g((total + 255) / 256, nmat);
        pack_b_kernel<<<g, 256, 0, stream>>>(B, K, ldb, col0, Ncols, hi, lo, matB, elems);
        PkB p; p.hi = hi; p.lo = lo; p.KG = KG; return p;
    };
    PkB pWe0 = packBn(We0, 16, HD, 0, HD, 1, 0);
    PkB pWn0 = packBn(Wn0, 64, HD, 0, HD, 1, 0);
    PkB pAWn[8], pAWe[8], pAWat[8];
    {
        PkB b = packBn(aWn, HD, HD, 0, HD, D, (size_t)HD * HD);
        for (int d = 0; d < D; ++d) { pAWn[d] = b; pAWn[d].hi = b.hi + d * elN; pAWn[d].lo = b.lo + d * elN; }
        b = packBn(aWe, 2 * HD, HD, 0, HD, D, (size_t)2 * HD * HD);
        for (int d = 0; d < D; ++d) { pAWe[d] = b; pAWe[d].hi = b.hi + d * elN; pAWe[d].lo = b.lo + d * elN; }
        b = packBn(aWat, HD, HD, 0, HD, D, (size_t)HD * HD);
        for (int d = 0; d < D; ++d) { pAWat[d] = b; pAWat[d].hi = b.hi + d * elN; pAWat[d].lo = b.lo + d * elN; }
    }
    short* ghiAll = pkcur; pkcur += (size_t)D * 6 * GRU_SL;
    short* gloAll = pkcur; pkcur += (size_t)D * 6 * GRU_SL;
    {
        int total = D * 6 * (GRU_SL / 8);
        pack_gru_kernel<<<(total + 255) / 256, 256, 0, stream>>>(aWih, aWhh, D, ghiAll, gloAll);
    }
    const short *gHi[8], *gLo[8];
    for (int d = 0; d < D; ++d) {
        gHi[d] = ghiAll + (size_t)d * 6 * GRU_SL;
        gLo[d] = gloAll + (size_t)d * 6 * GRU_SL;
    }
    PkB pMWat[4], pMWih[4], pMWhh[4];
    {
        PkB b = packBn(mWat, HD, HD, 0, HD, L, (size_t)HD * HD);
        for (int l = 0; l < L; ++l) { pMWat[l] = b; pMWat[l].hi = b.hi + l * elN; pMWat[l].lo = b.lo + l * elN; }
        b = packBn(mWih, HD, H3, 0, H3, L, (size_t)HD * H3);
        for (int l = 0; l < L; ++l) { pMWih[l] = b; pMWih[l].hi = b.hi + l * elN; pMWih[l].lo = b.lo + l * elN; }
        b = packBn(mWhh, HD, H3, 0, H3, L, (size_t)HD * H3);
        for (int l = 0; l < L; ++l) { pMWhh[l] = b; pMWhh[l].hi = b.hi + l * elN; pMWhh[l].lo = b.lo + l * elN; }
    }

    // ---- fixed workspace ----
    size_t off = ((size_t)((char*)pkcur - wsb) + 255) & ~(size_t)255;
    auto alloc = [&](size_t bytes) -> void* {
        void* p = (void*)(wsb + off);
        off += (bytes + 255) & ~(size_t)255;
        return p;
    };
    unsigned* npk = (unsigned*)alloc((size_t)N * HD * 4);
    unsigned* hpk = (unsigned*)alloc((size_t)N * HD * 4);
    float* sc_e = (float*)alloc((size_t)E * 4);
    float* zn   = (float*)alloc((size_t)2 * N * 4);   // hd2 | nsum (one memset)
    float* hd2  = zn;
    float* nsum = zn + N;
    float* sc_n = (float*)alloc((size_t)N * 4);
    float* sn   = (float*)alloc((size_t)G * HD * 4);
    float* gsum = (float*)alloc((size_t)G * 4);
    int* cnt    = (int*)alloc((size_t)(N + 1) * 4);
    int* rowptr = (int*)alloc((size_t)(N + 1) * 4);
    int* fillc  = (int*)alloc((size_t)N * 4);
    int* srcp   = (int*)alloc((size_t)E * 4);
    int* dstp   = (int*)alloc((size_t)E * 4);
    int* eidp   = (int*)alloc((size_t)E * 4);
    int* btot   = (int*)alloc(1024 * 4);

    // ---- overlay region OVR (msgpk | ctxpk | mol buffers) ----
    size_t ovr_off = off;
    size_t ctx_bytes = (size_t)N * HD * 4;
    size_t mol_bytes = 3 * ((size_t)G * HD * 4 + 256) + 2 * ((size_t)G * H3 * 4 + 256);
    size_t min_ovr = ctx_bytes > mol_bytes ? ctx_bytes : mol_bytes;
    int csr_mode, fullprec = 0;
    size_t mf = (size_t)E * HD * 4, mh = (size_t)E * HD * 2;
    if (ovr_off + (mf > min_ovr ? mf : min_ovr) <= ws_size) { csr_mode = 1; fullprec = 1; }
    else if (ovr_off + (mh > min_ovr ? mh : min_ovr) <= ws_size) { csr_mode = 1; fullprec = 0; }
    else if (ovr_off + min_ovr <= ws_size) { csr_mode = 0; }
    else {
        canary_kernel<<<(G + 255) / 256, 256, 0, stream>>>((float*)d_out, G);
        return;
    }
    void*     msgpk = (void*)(wsb + ovr_off);
    unsigned* ctxpk = (unsigned*)(wsb + ovr_off);
    size_t mo = ovr_off;
    auto molalloc = [&](size_t bytes) -> float* {
        float* p = (float*)(wsb + mo);
        mo += (bytes + 255) & ~(size_t)255;
        return p;
    };
    float* sbuf = molalloc((size_t)G * HD * 4);
    float* sctx = molalloc((size_t)G * HD * 4);
    float* Sg   = molalloc((size_t)G * HD * 4);
    float* gim  = molalloc((size_t)G * H3 * 4);
    float* ghm  = molalloc((size_t)G * H3 * 4);

    const int total_sc = N + 1;
    const int nb = (total_sc + 1023) / 1024;
    if (nb > 256) {
        canary_kernel<<<(G + 255) / 256, 256, 0, stream>>>((float*)d_out, G);
        return;
    }

    auto mgemm = [&](const void* A, int K, const PkB& pk, const float* bias, void* C,
                     int M, int Nc, int act, const float* rdw, float* rdout,
                     const float* rowmask, int outpk, int apk) {
        dim3 g((M + 63) / 64, Nc / 64);
        mfma_gemm<<<g, dim3(256), 0, stream>>>((const float*)A, K, pk.hi, pk.lo, pk.KG,
                                               bias, (float*)C, M, Nc, act, rdw, rdout,
                                               rowmask, outpk, apk);
    };

    // ---- CSR build ----
    hipMemsetAsync(cnt, 0, (size_t)(N + 1) * 4, stream);
    hipMemsetAsync(fillc, 0, (size_t)N * 4, stream);
    hist_kernel<<<(E + 255) / 256, 256, 0, stream>>>(dst, cnt, E);
    scan1_kernel<<<nb, 256, 0, stream>>>(cnt, rowptr, btot, total_sc);
    scan2_kernel<<<1, 256, 0, stream>>>(btot, nb);
    scan3_kernel<<<(total_sc + 255) / 256, 256, 0, stream>>>(rowptr, btot, total_sc);
    fill_kernel<<<(E + 255) / 256, 256, 0, stream>>>(src, dst, rowptr, fillc,
                                                     srcp, dstp, eidp, E);

    // ---- input embedding: n (packed) ----
    mgemm(node, 64, pWn0, bn0, npk, N, HD, 1, nullptr, nullptr, nullptr, 1, 0);

    // ---- atom-level message passing ----
    const int EB = (E + 63) / 64;
    for (int d = 0; d < D; ++d) {
        const float* bn_d  = abn  + (size_t)d * HD;
        const float* be_d  = abe  + (size_t)d * HD;
        const float* Wal_d = aWal + (size_t)d * 2 * HD;
        const float* bal_d = abal + d;
        const float* bat_d = abat + (size_t)d * HD;
        const float* bih_d = abih + (size_t)d * H3;
        const float* bhh_d = abhh + (size_t)d * H3;

        hipMemsetAsync(zn, 0, (size_t)2 * N * 4, stream);   // hd2 + nsum
        // h = lrelu(n @ Wn + bn) -> packed; rowdot hd2 = h . Wal[128:256]
        mgemm(npk, HD, pAWn[d], bn_d, hpk, N, HD, 1, Wal_d + HD, hd2, nullptr, 1, 1);
        // pass A: msg store (mode 0) + fused score/exp/nsum
        msg_pass_kernel<<<EB, 256, 0, stream>>>(hpk, srcp, dstp, eidp, edge,
                                                pWe0.hi, pWe0.lo, be0,
                                                pAWe[d].hi, pAWe[d].lo, be_d,
                                                Wal_d, hd2, bal_d,
                                                sc_e, nsum, nullptr, msgpk, fullprec, E,
                                                csr_mode ? 0 : 1);
        if (csr_mode) {
            ctx_gather_kernel<<<(N + 3) / 4, 256, 0, stream>>>(msgpk, sc_e, nsum, rowptr,
                                                               npk, N, fullprec);
        } else {
            hipMemsetAsync(npk, 0, (size_t)N * HD * 4, stream);
            msg_pass_kernel<<<EB, 256, 0, stream>>>(hpk, srcp, dstp, eidp, edge,
                                                    pWe0.hi, pWe0.lo, be0,
                                                    pAWe[d].hi, pAWe[d].lo, be_d,
                                                    Wal_d, hd2, bal_d,
                                                    sc_e, nsum, (float*)npk, nullptr, 0, E, 2);
        }
        // ctx = elu(S @ Wat + bat) -> packed; empty rows (nsum==0) -> 0
        mgemm(npk, HD, pAWat[d], bat_d, ctxpk, N, HD, 3, nullptr, nullptr, nsum, 1,
              csr_mode ? 1 : 0);
        // n = relu(GRU(ctx, h)) -> npk
        dim3 gg((N + 63) / 64, 2);
        gru_fused_kernel<<<gg, dim3(256), 0, stream>>>(ctxpk, hpk, gHi[d], gLo[d],
                                                       bih_d, bhh_d, npk, N);
    }

    // ---- molecule-level readout ----
    hipMemsetAsync(sn, 0, (size_t)G * HD * 4, stream);
    segsum_kernel<<<((size_t)N * HD + 255) / 256, 256, 0, stream>>>(npk, gid, sn, N);
    for (int l = 0; l < L; ++l) {
        const float* Wal_l = mWal + (size_t)l * 2 * HD;
        const float* bal_l = mbal + l;
        const float* bat_l = mbat + (size_t)l * HD;
        const float* bih_l = mbih + (size_t)l * H3;
        const float* bhh_l = mbhh + (size_t)l * H3;

        lrelu_copy_kernel<<<((size_t)G * HD + 255) / 256, 256, 0, stream>>>(sn, sbuf, (size_t)G * HD);
        hipMemsetAsync(gsum, 0, (size_t)G * 4, stream);
        score_kernel<<<(N + 3) / 4, 256, 0, stream>>>(npk, sbuf, gid, Wal_l, bal_l, sc_n, gsum, N);
        hipMemsetAsync(Sg, 0, (size_t)G * HD * 4, stream);
        seg_scale_sum_kernel<<<((size_t)N * HD + 255) / 256, 256, 0, stream>>>(npk, gid, sc_n, gsum, Sg, N);
        mgemm(Sg, HD, pMWat[l], bat_l, sctx, G, HD, 3, nullptr, nullptr, gsum, 0, 0);
        mgemm(sctx, HD, pMWih[l], bih_l, gim, G, H3, 0, nullptr, nullptr, nullptr, 0, 0);
        mgemm(sbuf, HD, pMWhh[l], bhh_l, ghm, G, H3, 0, nullptr, nullptr, nullptr, 0, 0);
        gru_gate_kernel<<<((size_t)G * HD + 255) / 256, 256, 0, stream>>>(gim, ghm, sbuf, sn, G);
    }

    // ---- final prediction ----
    final_kernel<<<(G + 3) / 4, 256, 0, stream>>>(sn, Wp, bp, (float*)d_out, G);
}